// Round 5
// baseline (259.795 us; speedup 1.0000x reference)
//
#include <hip/hip_runtime.h>

#define NN 131072
#define NE 8388608
#define NG 64
#define TSH 12
#define TSZ 4096          // nodes per tile
#define NTILE 32
#define NBUCK 1024        // NTILE*NTILE
#define SBLK 512          // scatter/hist blocks
#define CHUNK 16384       // edges per scatter/hist block (NE/SBLK)
#define PBLK 1024         // process blocks (= NBUCK)
#define NSLOT 6           // max graphs spanned by one 4096-node tile (sorted batch)
#define NCOPY 4
#define CSTR 68
// fallback (round-2) geometry
#define FB_NBLK 2048
#define FB_BLK 256

typedef unsigned uvec2 __attribute__((ext_vector_type(2)));

__device__ __forceinline__ uvec2 ldnt_u2(const uvec2* p) {
    return __builtin_nontemporal_load(p);
}

__device__ __forceinline__ int lower_bound_dev(const int* a, int n, int v) {
    int lo = 0, hi = n;
    while (lo < hi) { int mid = (lo + hi) >> 1; if (a[mid] < v) lo = mid + 1; else hi = mid; }
    return lo;
}

// ---------------- shared small kernels ----------------

// Pack {pos.x, pos.y, size.x (g in low 6 mantissa bits), size.y} per node.
__global__ void build_A_kernel(const float2* __restrict__ pos, const float2* __restrict__ sz,
                               const int* __restrict__ batch, float4* __restrict__ A) {
    int n = blockIdx.x * blockDim.x + threadIdx.x;
    if (n < NN) {
        float2 p = pos[n]; float2 s = sz[n];
        unsigned u = __float_as_uint(s.x);
        u = (u & ~63u) | (unsigned)batch[n];
        A[n] = make_float4(p.x, p.y, __uint_as_float(u), s.y);
    }
}

// Pack {pos/scale, graph_id_bits, 0} per node for pass 2.
__global__ void build_B_kernel(const float2* __restrict__ pos, const int* __restrict__ batch,
                               const float* __restrict__ scale, float4* __restrict__ B) {
    int n = blockIdx.x * blockDim.x + threadIdx.x;
    if (n < NN) {
        int g = batch[n];
        float s = scale[g];
        float2 p = pos[n];
        B[n] = make_float4(p.x / s, p.y / s, __int_as_float(g), 0.f);
    }
}

__global__ void reduce1_kernel(const float* __restrict__ rsum_p, const float* __restrict__ r2_p,
                               const float* __restrict__ ov_p, const float* __restrict__ cnt_p,
                               const int* __restrict__ batch, int nblk,
                               float* __restrict__ scale, float* __restrict__ gov,
                               float* __restrict__ gsize) {
    int g = blockIdx.x, tid = threadIdx.x;
    float a = 0.f, b = 0.f, c = 0.f, d = 0.f;
    for (int i = tid; i < nblk; i += 256) {
        a += rsum_p[g * nblk + i];
        b += r2_p[g * nblk + i];
        c += ov_p[g * nblk + i];
        d += cnt_p[g * nblk + i];
    }
    __shared__ float sa[256], sb[256], sc[256], sd[256];
    sa[tid] = a; sb[tid] = b; sc[tid] = c; sd[tid] = d;
    __syncthreads();
    for (int s = 128; s > 0; s >>= 1) {
        if (tid < s) { sa[tid] += sa[tid+s]; sb[tid] += sb[tid+s]; sc[tid] += sc[tid+s]; sd[tid] += sd[tid+s]; }
        __syncthreads();
    }
    if (tid == 0) {
        scale[g] = sb[0] / sa[0];
        gov[g]   = sc[0] / fmaxf(sd[0], 1.f);
        int lo = lower_bound_dev(batch, NN, g);
        int hi = lower_bound_dev(batch, NN, g + 1);
        gsize[g] = (float)(hi - lo);
    }
}

__global__ void reduce2_kernel(const float* __restrict__ st_p, const float* __restrict__ gsize,
                               const float* __restrict__ gov, int nblk, float* __restrict__ comb) {
    int g = blockIdx.x, tid = threadIdx.x;
    float a = 0.f;
    for (int i = tid; i < nblk; i += 256) a += st_p[g * nblk + i];
    __shared__ float sm[256];
    sm[tid] = a;
    __syncthreads();
    for (int s = 128; s > 0; s >>= 1) {
        if (tid < s) sm[tid] += sm[tid + s];
        __syncthreads();
    }
    if (tid == 0) {
        float n = gsize[g];
        comb[g] = sm[0] / (n * n) + gov[g];
    }
}

__global__ void final_kernel(const float* __restrict__ comb, float* __restrict__ out) {
    float v = comb[threadIdx.x];
    #pragma unroll
    for (int off = 32; off > 0; off >>= 1) v += __shfl_down(v, off);
    if (threadIdx.x == 0) out[0] = v * (1.0f / 64.0f);
}

// ---------------- sorted path ----------------

__global__ __launch_bounds__(512) void khist(const int* __restrict__ idx0, const int* __restrict__ idx1,
                                             unsigned* __restrict__ counts) {
    __shared__ unsigned hist[NBUCK];
    int tid = threadIdx.x, blk = blockIdx.x;
    for (int i = tid; i < NBUCK; i += 512) hist[i] = 0;
    __syncthreads();
    const int4* v0 = (const int4*)idx0 + blk * (CHUNK / 4);
    const int4* v1 = (const int4*)idx1 + blk * (CHUNK / 4);
    for (int i = tid; i < CHUNK / 4; i += 512) {
        int4 s4 = v0[i]; int4 t4 = v1[i];
        atomicAdd(&hist[(unsigned)(((s4.x >> TSH) << 5) | (t4.x >> TSH))], 1u);
        atomicAdd(&hist[(unsigned)(((s4.y >> TSH) << 5) | (t4.y >> TSH))], 1u);
        atomicAdd(&hist[(unsigned)(((s4.z >> TSH) << 5) | (t4.z >> TSH))], 1u);
        atomicAdd(&hist[(unsigned)(((s4.w >> TSH) << 5) | (t4.w >> TSH))], 1u);
    }
    __syncthreads();
    for (int j = tid; j < NBUCK; j += 512) counts[j * SBLK + blk] = hist[j];
}

// Per-bucket exclusive scan across blocks (in-place), emit row totals.
__global__ __launch_bounds__(512) void kscan_rows(unsigned* __restrict__ counts,
                                                  unsigned* __restrict__ rowtot) {
    int j = blockIdx.x, tid = threadIdx.x;
    unsigned* row = counts + j * SBLK;
    unsigned v = row[tid];
    __shared__ unsigned sc[512];
    sc[tid] = v; __syncthreads();
    for (int off = 1; off < 512; off <<= 1) {
        unsigned w = (tid >= off) ? sc[tid - off] : 0; __syncthreads();
        sc[tid] += w; __syncthreads();
    }
    row[tid] = sc[tid] - v;
    if (tid == 511) rowtot[j] = sc[511];
}

__global__ __launch_bounds__(1024) void kscan_base(const unsigned* __restrict__ rowtot,
                                                   unsigned* __restrict__ gbase) {
    int tid = threadIdx.x;
    __shared__ unsigned sc[1024];
    unsigned v = rowtot[tid];
    sc[tid] = v; __syncthreads();
    for (int off = 1; off < 1024; off <<= 1) {
        unsigned w = (tid >= off) ? sc[tid - off] : 0; __syncthreads();
        sc[tid] += w; __syncthreads();
    }
    gbase[tid] = sc[tid] - v;
    if (tid == 1023) gbase[1024] = sc[1023];
}

// One-pass scatter into bucket-sorted order. 8B records {local_s|local_t<<12, d_bits},
// written direct from registers (no LDS payload staging).
__global__ __launch_bounds__(1024) void kscatter(const int* __restrict__ idx0, const int* __restrict__ idx1,
                                                 const float* __restrict__ attr,
                                                 const unsigned* __restrict__ rel,
                                                 const unsigned* __restrict__ gbase,
                                                 uvec2* __restrict__ srt) {
    __shared__ unsigned hist[NBUCK], loc[NBUCK], wbase[NBUCK], sc[NBUCK];
    int tid = threadIdx.x, blk = blockIdx.x;
    hist[tid] = 0;
    __syncthreads();
    unsigned es[16], et[16], ed[16], eb[16];
    const int4* v0 = (const int4*)idx0 + blk * (CHUNK / 4);
    const int4* v1 = (const int4*)idx1 + blk * (CHUNK / 4);
    const int4* va = (const int4*)attr + blk * (CHUNK / 4);
    #pragma unroll
    for (int k = 0; k < 4; ++k) {
        int i = tid + k * 1024;
        int4 s4 = v0[i]; int4 t4 = v1[i]; int4 d4 = va[i];
        es[4*k+0] = s4.x; es[4*k+1] = s4.y; es[4*k+2] = s4.z; es[4*k+3] = s4.w;
        et[4*k+0] = t4.x; et[4*k+1] = t4.y; et[4*k+2] = t4.z; et[4*k+3] = t4.w;
        ed[4*k+0] = d4.x; ed[4*k+1] = d4.y; ed[4*k+2] = d4.z; ed[4*k+3] = d4.w;
    }
    #pragma unroll
    for (int k = 0; k < 16; ++k) {
        eb[k] = ((es[k] >> TSH) << 5) | (et[k] >> TSH);
        atomicAdd(&hist[eb[k]], 1u);
    }
    __syncthreads();
    unsigned h = hist[tid];
    sc[tid] = h; __syncthreads();
    for (int off = 1; off < 1024; off <<= 1) {
        unsigned w = (tid >= off) ? sc[tid - off] : 0; __syncthreads();
        sc[tid] += w; __syncthreads();
    }
    unsigned ex = sc[tid] - h;
    loc[tid]   = ex;
    wbase[tid] = gbase[tid] + rel[tid * SBLK + blk] - ex;
    __syncthreads();
    #pragma unroll
    for (int k = 0; k < 16; ++k) {
        unsigned b = eb[k];
        unsigned p = atomicAdd(&loc[b], 1u);
        uvec2 rec;
        rec.x = (es[k] & (TSZ - 1)) | ((et[k] & (TSZ - 1)) << 12);
        rec.y = ed[k];
        srt[wbase[b] + p] = rec;
    }
}

// Process pass 1: both tiles in LDS, per-lane register slot accumulation (no per-edge atomics).
__global__ __launch_bounds__(512) void kproc1(const uvec2* __restrict__ srt,
                                              const unsigned* __restrict__ gbase,
                                              const float4* __restrict__ A,
                                              float* __restrict__ rsum_p, float* __restrict__ r2_p,
                                              float* __restrict__ ov_p, float* __restrict__ cnt_p) {
    __shared__ float4 tS[TSZ], tT[TSZ];
    __shared__ float acc_ws[8][NSLOT * 4];
    __shared__ float ovf[NG * 4];            // overflow path: never taken in practice
    int tid = threadIdx.x, bid = blockIdx.x;
    const float4* As = A + (bid >> 5) * TSZ;
    const float4* At = A + (bid & 31) * TSZ;
    for (int i = tid; i < TSZ; i += 512) { tS[i] = As[i]; tT[i] = At[i]; }
    for (int i = tid; i < NG * 4; i += 512) ovf[i] = 0.f;
    __syncthreads();
    const int g0 = (int)(__float_as_uint(tS[0].z) & 63u);  // graph of s-tile's first node
    float ar[NSLOT], a2[NSLOT], ao[NSLOT], ac[NSLOT];
    #pragma unroll
    for (int j = 0; j < NSLOT; ++j) { ar[j] = 0.f; a2[j] = 0.f; ao[j] = 0.f; ac[j] = 0.f; }
    const int lo = (int)gbase[bid], hi = (int)gbase[bid + 1];
    for (int i = lo + tid; i < hi; i += 512) {
        uvec2 rec = ldnt_u2(srt + i);
        float d = __uint_as_float(rec.y);
        float4 a = tS[rec.x & (TSZ - 1)];
        float4 b = tT[(rec.x >> 12) & (TSZ - 1)];
        int dg = (int)(__float_as_uint(a.z) & 63u) - g0;   // >= 0 (batch sorted)
        float dx = a.x - b.x, dy = a.y - b.y;
        float eu = sqrtf(dx * dx + dy * dy);
        float r = eu / d;
        float r2 = r * r;
        float ox = fmaxf((a.z + b.z) * 0.5f - fabsf(dx), 0.f);
        float oy = fmaxf((a.w + b.w) * 0.5f - fabsf(dy), 0.f);
        float nov = (ox * oy) / (a.z + a.w + b.z + b.w);
        if (__builtin_expect(dg >= NSLOT, 0)) {
            int gg = g0 + dg;
            atomicAdd(&ovf[gg * 4 + 0], r);
            atomicAdd(&ovf[gg * 4 + 1], r2);
            atomicAdd(&ovf[gg * 4 + 2], nov);
            atomicAdd(&ovf[gg * 4 + 3], 1.f);
        } else {
            #pragma unroll
            for (int j = 0; j < NSLOT; ++j) {
                float m = (dg == j) ? 1.f : 0.f;
                ar[j] = fmaf(m, r, ar[j]);
                a2[j] = fmaf(m, r2, a2[j]);
                ao[j] = fmaf(m, nov, ao[j]);
                ac[j] += m;
            }
        }
    }
    #pragma unroll
    for (int j = 0; j < NSLOT; ++j) {
        for (int off = 1; off < 64; off <<= 1) {
            ar[j] += __shfl_xor(ar[j], off);
            a2[j] += __shfl_xor(a2[j], off);
            ao[j] += __shfl_xor(ao[j], off);
            ac[j] += __shfl_xor(ac[j], off);
        }
    }
    int wv = tid >> 6, ln = tid & 63;
    if (ln == 0) {
        #pragma unroll
        for (int j = 0; j < NSLOT; ++j) {
            acc_ws[wv][j * 4 + 0] = ar[j];
            acc_ws[wv][j * 4 + 1] = a2[j];
            acc_ws[wv][j * 4 + 2] = ao[j];
            acc_ws[wv][j * 4 + 3] = ac[j];
        }
    }
    __syncthreads();
    if (tid < NG) {
        int j = tid - g0;
        float vr = ovf[tid * 4 + 0], v2 = ovf[tid * 4 + 1];
        float vo = ovf[tid * 4 + 2], vc = ovf[tid * 4 + 3];
        if (j >= 0 && j < NSLOT) {
            #pragma unroll
            for (int w = 0; w < 8; ++w) {
                vr += acc_ws[w][j * 4 + 0];
                v2 += acc_ws[w][j * 4 + 1];
                vo += acc_ws[w][j * 4 + 2];
                vc += acc_ws[w][j * 4 + 3];
            }
        }
        rsum_p[tid * PBLK + bid] = vr;
        r2_p[tid * PBLK + bid]   = v2;
        ov_p[tid * PBLK + bid]   = vo;
        cnt_p[tid * PBLK + bid]  = vc;
    }
}

// Process pass 2: stress with scaled positions, register-slot accumulation.
__global__ __launch_bounds__(512) void kproc2(const uvec2* __restrict__ srt,
                                              const unsigned* __restrict__ gbase,
                                              const float4* __restrict__ B,
                                              float* __restrict__ st_p) {
    __shared__ float4 tS[TSZ], tT[TSZ];
    __shared__ float acc_ws[8][NSLOT];
    __shared__ float ovf[NG];
    int tid = threadIdx.x, bid = blockIdx.x;
    const float4* Bs = B + (bid >> 5) * TSZ;
    const float4* Bt = B + (bid & 31) * TSZ;
    for (int i = tid; i < TSZ; i += 512) { tS[i] = Bs[i]; tT[i] = Bt[i]; }
    for (int i = tid; i < NG; i += 512) ovf[i] = 0.f;
    __syncthreads();
    const int g0 = __float_as_int(tS[0].z);
    float ast[NSLOT];
    #pragma unroll
    for (int j = 0; j < NSLOT; ++j) ast[j] = 0.f;
    const int lo = (int)gbase[bid], hi = (int)gbase[bid + 1];
    for (int i = lo + tid; i < hi; i += 512) {
        uvec2 rec = ldnt_u2(srt + i);
        float d = __uint_as_float(rec.y);
        float4 a = tS[rec.x & (TSZ - 1)];
        float4 b = tT[(rec.x >> 12) & (TSZ - 1)];
        int dg = __float_as_int(a.z) - g0;
        float dx = a.x - b.x, dy = a.y - b.y;
        float eu2 = sqrtf(dx * dx + dy * dy);
        float q = (eu2 - d) / d;
        float q2 = q * q;
        if (__builtin_expect(dg >= NSLOT, 0)) {
            atomicAdd(&ovf[g0 + dg], q2);
        } else {
            #pragma unroll
            for (int j = 0; j < NSLOT; ++j) {
                float m = (dg == j) ? 1.f : 0.f;
                ast[j] = fmaf(m, q2, ast[j]);
            }
        }
    }
    #pragma unroll
    for (int j = 0; j < NSLOT; ++j) {
        for (int off = 1; off < 64; off <<= 1) ast[j] += __shfl_xor(ast[j], off);
    }
    int wv = tid >> 6, ln = tid & 63;
    if (ln == 0) {
        #pragma unroll
        for (int j = 0; j < NSLOT; ++j) acc_ws[wv][j] = ast[j];
    }
    __syncthreads();
    if (tid < NG) {
        int j = tid - g0;
        float v = ovf[tid];
        if (j >= 0 && j < NSLOT) {
            #pragma unroll
            for (int w = 0; w < 8; ++w) v += acc_ws[w][j];
        }
        st_p[tid * PBLK + bid] = v;
    }
}

// ---------------- fallback path (round-2 gather kernels) ----------------

__global__ __launch_bounds__(FB_BLK) void pass1_fb(
    const int* __restrict__ idx0, const int* __restrict__ idx1,
    const float* __restrict__ attr, const float4* __restrict__ A,
    float* __restrict__ rsum_p, float* __restrict__ r2_p,
    float* __restrict__ ov_p, float* __restrict__ cnt_p) {
    __shared__ float sb_r[NCOPY*CSTR], sb_r2[NCOPY*CSTR], sb_ov[NCOPY*CSTR], sb_c[NCOPY*CSTR];
    int tid = threadIdx.x;
    for (int i = tid; i < NCOPY*CSTR; i += FB_BLK) { sb_r[i]=0.f; sb_r2[i]=0.f; sb_ov[i]=0.f; sb_c[i]=0.f; }
    __syncthreads();
    const int copy_off = (tid & (NCOPY - 1)) * CSTR;
    const int4* v0 = (const int4*)idx0;
    const int4* v1 = (const int4*)idx1;
    const float4* va = (const float4*)attr;
    const int gid = blockIdx.x * FB_BLK + tid;
    const int GRID = FB_NBLK * FB_BLK;
    for (int it = 0; it < 4; ++it) {
        int i = gid + it * GRID;
        int4 s4 = v0[i]; int4 t4 = v1[i]; float4 d4 = va[i];
        int   ss[4] = {s4.x, s4.y, s4.z, s4.w};
        int   tt[4] = {t4.x, t4.y, t4.z, t4.w};
        float dd[4] = {d4.x, d4.y, d4.z, d4.w};
        #pragma unroll
        for (int k = 0; k < 4; ++k) {
            float4 as_ = A[ss[k]], at_ = A[tt[k]];
            int g = (int)(__float_as_uint(as_.z) & 63u);
            int b = copy_off + g;
            float dx = as_.x - at_.x, dy = as_.y - at_.y;
            float eu = sqrtf(dx * dx + dy * dy);
            float r = eu / dd[k];
            atomicAdd(&sb_r[b], r);
            atomicAdd(&sb_r2[b], r * r);
            float ox = fmaxf((as_.z + at_.z) * 0.5f - fabsf(dx), 0.f);
            float oy = fmaxf((as_.w + at_.w) * 0.5f - fabsf(dy), 0.f);
            atomicAdd(&sb_ov[b], (ox * oy) / (as_.z + as_.w + at_.z + at_.w));
            atomicAdd(&sb_c[b], 1.f);
        }
    }
    __syncthreads();
    if (tid < NG) {
        float r = 0.f, r2 = 0.f, ov = 0.f, c = 0.f;
        #pragma unroll
        for (int cp = 0; cp < NCOPY; ++cp) {
            int b = cp * CSTR + tid;
            r += sb_r[b]; r2 += sb_r2[b]; ov += sb_ov[b]; c += sb_c[b];
        }
        int o = tid * FB_NBLK + blockIdx.x;
        rsum_p[o] = r; r2_p[o] = r2; ov_p[o] = ov; cnt_p[o] = c;
    }
}

__global__ __launch_bounds__(FB_BLK) void pass2_fb(
    const int* __restrict__ idx0, const int* __restrict__ idx1,
    const float* __restrict__ attr, const float4* __restrict__ B,
    float* __restrict__ st_p) {
    __shared__ float sbn[NCOPY*CSTR];
    int tid = threadIdx.x;
    for (int i = tid; i < NCOPY*CSTR; i += FB_BLK) sbn[i] = 0.f;
    __syncthreads();
    const int copy_off = (tid & (NCOPY - 1)) * CSTR;
    const int4* v0 = (const int4*)idx0;
    const int4* v1 = (const int4*)idx1;
    const float4* va = (const float4*)attr;
    const int gid = blockIdx.x * FB_BLK + tid;
    const int GRID = FB_NBLK * FB_BLK;
    for (int it = 0; it < 4; ++it) {
        int i = gid + it * GRID;
        int4 s4 = v0[i]; int4 t4 = v1[i]; float4 d4 = va[i];
        int   ss[4] = {s4.x, s4.y, s4.z, s4.w};
        int   tt[4] = {t4.x, t4.y, t4.z, t4.w};
        float dd[4] = {d4.x, d4.y, d4.z, d4.w};
        #pragma unroll
        for (int k = 0; k < 4; ++k) {
            float4 bs = B[ss[k]], bt = B[tt[k]];
            int g = __float_as_int(bs.z);
            float dx = bs.x - bt.x, dy = bs.y - bt.y;
            float eu2 = sqrtf(dx * dx + dy * dy);
            float q = (eu2 - dd[k]) / dd[k];
            atomicAdd(&sbn[copy_off + g], q * q);
        }
    }
    __syncthreads();
    if (tid < NG) {
        float v = 0.f;
        #pragma unroll
        for (int cp = 0; cp < NCOPY; ++cp) v += sbn[cp * CSTR + tid];
        st_p[tid * FB_NBLK + blockIdx.x] = v;
    }
}

// ---------------- host ----------------

extern "C" void kernel_launch(void* const* d_in, const int* in_sizes, int n_in,
                              void* d_out, int out_size, void* d_ws, size_t ws_size,
                              hipStream_t stream) {
    const float* node_pos   = (const float*)d_in[0];
    const float* node_sizes = (const float*)d_in[1];
    const float* attr       = (const float*)d_in[2];
    const int*   eidx       = (const int*)d_in[3];
    const int*   batch      = (const int*)d_in[4];
    float* out = (float*)d_out;
    unsigned* ws = (unsigned*)d_ws;
    const int* idx0 = eidx;
    const int* idx1 = eidx + NE;

    // sorted-path layout (u32 units)
    const size_t o_srt    = 0;                               // 2*NE u32 (8B records)
    const size_t o_rel    = o_srt + (size_t)2 * NE;
    const size_t o_rowtot = o_rel + (size_t)NBUCK * SBLK;
    const size_t o_gbase  = o_rowtot + 1024;
    const size_t o_A      = o_gbase + 1028;                  // 16B-aligned
    const size_t o_B      = o_A + (size_t)4 * NN;
    const size_t o_part   = o_B + (size_t)4 * NN;
    const size_t o_small  = o_part + (size_t)4 * NG * PBLK;
    const size_t need     = (o_small + 256) * 4;

    if (ws_size >= need) {
        unsigned* rel    = ws + o_rel;
        unsigned* rowtot = ws + o_rowtot;
        unsigned* gbase  = ws + o_gbase;
        uvec2*    srt    = (uvec2*)(ws + o_srt);
        float4* A = (float4*)(ws + o_A);
        float4* B = (float4*)(ws + o_B);
        float* rsum_p = (float*)(ws + o_part);
        float* r2_p   = rsum_p + NG * PBLK;
        float* ov_p   = r2_p + NG * PBLK;
        float* cnt_p  = ov_p + NG * PBLK;
        float* st_p   = rsum_p;                 // alias: pass2 after reduce1
        float* scale  = (float*)(ws + o_small);
        float* gov    = scale + 64;
        float* gsize  = gov + 64;
        float* comb   = gsize + 64;

        build_A_kernel<<<NN / 256, 256, 0, stream>>>((const float2*)node_pos,
                                                     (const float2*)node_sizes, batch, A);
        khist<<<SBLK, 512, 0, stream>>>(idx0, idx1, rel);
        kscan_rows<<<NBUCK, 512, 0, stream>>>(rel, rowtot);
        kscan_base<<<1, 1024, 0, stream>>>(rowtot, gbase);
        kscatter<<<SBLK, 1024, 0, stream>>>(idx0, idx1, attr, rel, gbase, srt);
        kproc1<<<PBLK, 512, 0, stream>>>(srt, gbase, A, rsum_p, r2_p, ov_p, cnt_p);
        reduce1_kernel<<<NG, 256, 0, stream>>>(rsum_p, r2_p, ov_p, cnt_p, batch, PBLK,
                                               scale, gov, gsize);
        build_B_kernel<<<NN / 256, 256, 0, stream>>>((const float2*)node_pos, batch, scale, B);
        kproc2<<<PBLK, 512, 0, stream>>>(srt, gbase, B, st_p);
        reduce2_kernel<<<NG, 256, 0, stream>>>(st_p, gsize, gov, PBLK, comb);
        final_kernel<<<1, 64, 0, stream>>>(comb, out);
    } else {
        // fallback: round-2 gather path (~6.3 MB ws)
        const int P = NG * FB_NBLK;
        float* rsum_p = (float*)ws;
        float* r2_p   = rsum_p + P;
        float* ov_p   = r2_p + P;
        float* cnt_p  = ov_p + P;
        float* st_p   = rsum_p;
        float* scale  = cnt_p + P;
        float* gov    = scale + 64;
        float* gsize  = gov + 64;
        float* comb   = gsize + 64;
        float4* A = (float4*)(comb + 64);
        float4* B = A + NN;

        build_A_kernel<<<NN / 256, 256, 0, stream>>>((const float2*)node_pos,
                                                     (const float2*)node_sizes, batch, A);
        pass1_fb<<<FB_NBLK, FB_BLK, 0, stream>>>(idx0, idx1, attr, A, rsum_p, r2_p, ov_p, cnt_p);
        reduce1_kernel<<<NG, 256, 0, stream>>>(rsum_p, r2_p, ov_p, cnt_p, batch, FB_NBLK,
                                               scale, gov, gsize);
        build_B_kernel<<<NN / 256, 256, 0, stream>>>((const float2*)node_pos, batch, scale, B);
        pass2_fb<<<FB_NBLK, FB_BLK, 0, stream>>>(idx0, idx1, attr, B, st_p);
        reduce2_kernel<<<NG, 256, 0, stream>>>(st_p, gsize, gov, FB_NBLK, comb);
        final_kernel<<<1, 64, 0, stream>>>(comb, out);
    }
}

// Round 6
// 147.089 us; speedup vs baseline: 1.7663x; 1.7663x over previous
//
#include <hip/hip_runtime.h>

#define NN 131072
#define NE 8388608
#define NG 64
#define TSH 12
#define TSZ 4096          // nodes per tile
#define NTILE 32
#define NBUCK 1024        // NTILE*NTILE
#define SBLK 512          // hist/scatter blocks
#define CHUNK 16384       // edges per hist/scatter block (NE/SBLK)
#define PBLK 1024         // process blocks (= NBUCK)
#define NSLOT 6           // max graphs spanned by one 4096-node tile (sorted batch)
#define NCOPY 4
#define CSTR 68
// fallback geometry
#define FB_NBLK 2048
#define FB_BLK 256

typedef unsigned uvec2 __attribute__((ext_vector_type(2)));

__device__ __forceinline__ uvec2 ldnt_u2(const uvec2* p) {
    return __builtin_nontemporal_load(p);
}

__device__ __forceinline__ int lower_bound_dev(const int* a, int n, int v) {
    int lo = 0, hi = n;
    while (lo < hi) { int mid = (lo + hi) >> 1; if (a[mid] < v) lo = mid + 1; else hi = mid; }
    return lo;
}

// ---------------- shared small kernels ----------------

// Pack {pos.x, pos.y, size.x (g in low 6 mantissa bits), size.y} per node.
__global__ void build_A_kernel(const float2* __restrict__ pos, const float2* __restrict__ sz,
                               const int* __restrict__ batch, float4* __restrict__ A) {
    int n = blockIdx.x * blockDim.x + threadIdx.x;
    if (n < NN) {
        float2 p = pos[n]; float2 s = sz[n];
        unsigned u = __float_as_uint(s.x);
        u = (u & ~63u) | (unsigned)batch[n];
        A[n] = make_float4(p.x, p.y, __uint_as_float(u), s.y);
    }
}

// Final per-graph math using the identity graph_stress = cnt - S1^2/S2
// (since scale = S2/S1 and edge_stress = (r/scale - 1)^2 sums to cnt - S1^2/S2).
__global__ void reduce_final1(const float* __restrict__ rsum_p, const float* __restrict__ r2_p,
                              const float* __restrict__ ov_p, const float* __restrict__ cnt_p,
                              const int* __restrict__ batch, int nblk,
                              float* __restrict__ comb) {
    int g = blockIdx.x, tid = threadIdx.x;
    float a = 0.f, b = 0.f, c = 0.f, d = 0.f;
    for (int i = tid; i < nblk; i += 256) {
        a += rsum_p[g * nblk + i];
        b += r2_p[g * nblk + i];
        c += ov_p[g * nblk + i];
        d += cnt_p[g * nblk + i];
    }
    __shared__ float sa[256], sb[256], sc[256], sd[256];
    sa[tid] = a; sb[tid] = b; sc[tid] = c; sd[tid] = d;
    __syncthreads();
    for (int s = 128; s > 0; s >>= 1) {
        if (tid < s) { sa[tid] += sa[tid+s]; sb[tid] += sb[tid+s]; sc[tid] += sc[tid+s]; sd[tid] += sd[tid+s]; }
        __syncthreads();
    }
    if (tid == 0) {
        float S1 = sa[0], S2 = sb[0], Sov = sc[0], cnt = sd[0];
        int lo = lower_bound_dev(batch, NN, g);
        int hi = lower_bound_dev(batch, NN, g + 1);
        float n = (float)(hi - lo);
        float stress = cnt - (S1 * S1) / S2;
        comb[g] = stress / (n * n) + Sov / fmaxf(cnt, 1.f);
    }
}

__global__ void final_kernel(const float* __restrict__ comb, float* __restrict__ out) {
    float v = comb[threadIdx.x];
    #pragma unroll
    for (int off = 32; off > 0; off >>= 1) v += __shfl_down(v, off);
    if (threadIdx.x == 0) out[0] = v * (1.0f / 64.0f);
}

// ---------------- sorted path ----------------

// counts layout: counts[blk * NBUCK + j]  (block-major, coalesced here and in kscatter)
__global__ __launch_bounds__(512) void khist(const int* __restrict__ idx0, const int* __restrict__ idx1,
                                             unsigned* __restrict__ counts) {
    __shared__ unsigned hist[2 * 1032];
    int tid = threadIdx.x, blk = blockIdx.x;
    for (int i = tid; i < 2 * 1032; i += 512) hist[i] = 0;
    __syncthreads();
    const int co = (tid & 1) * 1032;
    const int4* v0 = (const int4*)idx0 + blk * (CHUNK / 4);
    const int4* v1 = (const int4*)idx1 + blk * (CHUNK / 4);
    for (int i = tid; i < CHUNK / 4; i += 512) {
        int4 s4 = v0[i]; int4 t4 = v1[i];
        atomicAdd(&hist[co + (((s4.x >> TSH) << 5) | (t4.x >> TSH))], 1u);
        atomicAdd(&hist[co + (((s4.y >> TSH) << 5) | (t4.y >> TSH))], 1u);
        atomicAdd(&hist[co + (((s4.z >> TSH) << 5) | (t4.z >> TSH))], 1u);
        atomicAdd(&hist[co + (((s4.w >> TSH) << 5) | (t4.w >> TSH))], 1u);
    }
    __syncthreads();
    for (int j = tid; j < NBUCK; j += 512)
        counts[(size_t)blk * NBUCK + j] = hist[j] + hist[1032 + j];
}

// Per-bucket exclusive scan across blocks, 16 buckets per block (tiled to keep
// the block-major counts layout coalesced). In-place; emits per-bucket totals.
__global__ __launch_bounds__(512) void kscan16(unsigned* __restrict__ counts,
                                               unsigned* __restrict__ rowtot) {
    const int j0 = blockIdx.x * 16;
    const int tid = threadIdx.x;               // = source block index
    const int ln = tid & 63, wv = tid >> 6;
    unsigned* base = counts + (size_t)tid * NBUCK + j0;
    uint4 q0 = *(const uint4*)(base);
    uint4 q1 = *(const uint4*)(base + 4);
    uint4 q2 = *(const uint4*)(base + 8);
    uint4 q3 = *(const uint4*)(base + 12);
    unsigned v[16] = {q0.x,q0.y,q0.z,q0.w, q1.x,q1.y,q1.z,q1.w,
                      q2.x,q2.y,q2.z,q2.w, q3.x,q3.y,q3.z,q3.w};
    unsigned ex[16];
    __shared__ unsigned wpart[8];
    #pragma unroll
    for (int k = 0; k < 16; ++k) {
        unsigned x = v[k];
        #pragma unroll
        for (int off = 1; off < 64; off <<= 1) {
            unsigned y = __shfl_up(x, off);
            if (ln >= off) x += y;
        }
        if (ln == 63) wpart[wv] = x;
        __syncthreads();
        unsigned wb = 0;
        for (int w = 0; w < 8; ++w) wb += (w < wv) ? wpart[w] : 0;
        ex[k] = wb + x - v[k];
        if (tid == 511) rowtot[j0 + k] = wb + x;
        __syncthreads();
    }
    *(uint4*)(base)      = make_uint4(ex[0], ex[1], ex[2], ex[3]);
    *(uint4*)(base + 4)  = make_uint4(ex[4], ex[5], ex[6], ex[7]);
    *(uint4*)(base + 8)  = make_uint4(ex[8], ex[9], ex[10], ex[11]);
    *(uint4*)(base + 12) = make_uint4(ex[12], ex[13], ex[14], ex[15]);
}

__global__ __launch_bounds__(1024) void kscan_base(const unsigned* __restrict__ rowtot,
                                                   unsigned* __restrict__ gbase) {
    int tid = threadIdx.x;
    __shared__ unsigned sc[1024];
    unsigned v = rowtot[tid];
    sc[tid] = v; __syncthreads();
    for (int off = 1; off < 1024; off <<= 1) {
        unsigned w = (tid >= off) ? sc[tid - off] : 0; __syncthreads();
        sc[tid] += w; __syncthreads();
    }
    gbase[tid] = sc[tid] - v;
    if (tid == 1023) gbase[1024] = sc[1023];
}

// LDS-staged scatter into bucket-sorted order. 8B records:
//   rx = s_local(12) | t_local(12)<<12 | (bucket&255)<<24
//   ry = (d_bits & ~3) | bucket>>8      (2 low mantissa bits of d stolen;
//        rel err 2.4e-7, cancels in S1^2/S2 since it's a per-edge scale on r)
__global__ __launch_bounds__(1024) void kscatter(const int* __restrict__ idx0, const int* __restrict__ idx1,
                                                 const float* __restrict__ attr,
                                                 const unsigned* __restrict__ rel,
                                                 const unsigned* __restrict__ gbase,
                                                 uvec2* __restrict__ srt) {
    __shared__ uvec2 pay[CHUNK];                       // 128 KB
    __shared__ unsigned hist[NBUCK], loc[NBUCK], wbase[NBUCK];
    __shared__ unsigned wpart[16];
    int tid = threadIdx.x, blk = blockIdx.x;
    const int ln = tid & 63, wv = tid >> 6;
    hist[tid] = 0;
    __syncthreads();
    unsigned rx[16], ry[16];
    const int4* v0 = (const int4*)idx0 + blk * (CHUNK / 4);
    const int4* v1 = (const int4*)idx1 + blk * (CHUNK / 4);
    const int4* va = (const int4*)attr + blk * (CHUNK / 4);
    #pragma unroll
    for (int k = 0; k < 4; ++k) {
        int i = tid + k * 1024;
        int4 s4 = v0[i]; int4 t4 = v1[i]; int4 d4 = va[i];
        unsigned ss[4] = {(unsigned)s4.x, (unsigned)s4.y, (unsigned)s4.z, (unsigned)s4.w};
        unsigned tt[4] = {(unsigned)t4.x, (unsigned)t4.y, (unsigned)t4.z, (unsigned)t4.w};
        unsigned dd[4] = {(unsigned)d4.x, (unsigned)d4.y, (unsigned)d4.z, (unsigned)d4.w};
        #pragma unroll
        for (int m = 0; m < 4; ++m) {
            unsigned j = ((ss[m] >> TSH) << 5) | (tt[m] >> TSH);
            rx[4*k+m] = (ss[m] & (TSZ-1)) | ((tt[m] & (TSZ-1)) << 12) | ((j & 255u) << 24);
            ry[4*k+m] = (dd[m] & ~3u) | (j >> 8);
            atomicAdd(&hist[j], 1u);
        }
    }
    __syncthreads();
    // exclusive scan of hist via wave scans
    unsigned h = hist[tid];
    unsigned x = h;
    #pragma unroll
    for (int off = 1; off < 64; off <<= 1) {
        unsigned y = __shfl_up(x, off);
        if (ln >= off) x += y;
    }
    if (ln == 63) wpart[wv] = x;
    __syncthreads();
    unsigned wb = 0;
    for (int w = 0; w < 16; ++w) wb += (w < wv) ? wpart[w] : 0;
    unsigned ex = wb + x - h;
    loc[tid]   = ex;
    wbase[tid] = gbase[tid] + rel[(size_t)blk * NBUCK + tid] - ex;
    __syncthreads();
    #pragma unroll
    for (int k = 0; k < 16; ++k) {
        unsigned j = ((rx[k] >> 24) & 255u) | ((ry[k] & 3u) << 8);
        unsigned p = atomicAdd(&loc[j], 1u);
        uvec2 r; r.x = rx[k]; r.y = ry[k];
        pay[p] = r;
    }
    __syncthreads();
    for (int p = tid; p < CHUNK; p += 1024) {
        uvec2 r = pay[p];
        unsigned j = ((r.x >> 24) & 255u) | ((r.y & 3u) << 8);
        srt[wbase[j] + p] = r;
    }
}

// Process pass: both tiles in LDS, per-lane register-slot accumulation (no per-edge atomics).
__global__ __launch_bounds__(512) void kproc1(const uvec2* __restrict__ srt,
                                              const unsigned* __restrict__ gbase,
                                              const float4* __restrict__ A,
                                              float* __restrict__ rsum_p, float* __restrict__ r2_p,
                                              float* __restrict__ ov_p, float* __restrict__ cnt_p) {
    __shared__ float4 tS[TSZ], tT[TSZ];
    __shared__ float acc_ws[8][NSLOT * 4];
    __shared__ float ovf[NG * 4];            // overflow path: never taken in practice
    int tid = threadIdx.x, bid = blockIdx.x;
    const float4* As = A + (bid >> 5) * TSZ;
    const float4* At = A + (bid & 31) * TSZ;
    for (int i = tid; i < TSZ; i += 512) { tS[i] = As[i]; tT[i] = At[i]; }
    for (int i = tid; i < NG * 4; i += 512) ovf[i] = 0.f;
    __syncthreads();
    const int g0 = (int)(__float_as_uint(tS[0].z) & 63u);
    float ar[NSLOT], a2[NSLOT], ao[NSLOT], ac[NSLOT];
    #pragma unroll
    for (int j = 0; j < NSLOT; ++j) { ar[j] = 0.f; a2[j] = 0.f; ao[j] = 0.f; ac[j] = 0.f; }
    const int lo = (int)gbase[bid], hi = (int)gbase[bid + 1];
    for (int i = lo + tid; i < hi; i += 512) {
        uvec2 rec = ldnt_u2(srt + i);
        float d = __uint_as_float(rec.y & ~3u);
        float4 a = tS[rec.x & (TSZ - 1)];
        float4 b = tT[(rec.x >> 12) & (TSZ - 1)];
        int dg = (int)(__float_as_uint(a.z) & 63u) - g0;   // >= 0 (batch sorted)
        float dx = a.x - b.x, dy = a.y - b.y;
        float eu = sqrtf(dx * dx + dy * dy);
        float r = eu / d;
        float r2 = r * r;
        float ox = fmaxf((a.z + b.z) * 0.5f - fabsf(dx), 0.f);
        float oy = fmaxf((a.w + b.w) * 0.5f - fabsf(dy), 0.f);
        float nov = (ox * oy) / (a.z + a.w + b.z + b.w);
        if (__builtin_expect(dg >= NSLOT, 0)) {
            int gg = g0 + dg;
            atomicAdd(&ovf[gg * 4 + 0], r);
            atomicAdd(&ovf[gg * 4 + 1], r2);
            atomicAdd(&ovf[gg * 4 + 2], nov);
            atomicAdd(&ovf[gg * 4 + 3], 1.f);
        } else {
            #pragma unroll
            for (int j = 0; j < NSLOT; ++j) {
                float m = (dg == j) ? 1.f : 0.f;
                ar[j] = fmaf(m, r, ar[j]);
                a2[j] = fmaf(m, r2, a2[j]);
                ao[j] = fmaf(m, nov, ao[j]);
                ac[j] += m;
            }
        }
    }
    #pragma unroll
    for (int j = 0; j < NSLOT; ++j) {
        for (int off = 1; off < 64; off <<= 1) {
            ar[j] += __shfl_xor(ar[j], off);
            a2[j] += __shfl_xor(a2[j], off);
            ao[j] += __shfl_xor(ao[j], off);
            ac[j] += __shfl_xor(ac[j], off);
        }
    }
    int wv = tid >> 6, ln = tid & 63;
    if (ln == 0) {
        #pragma unroll
        for (int j = 0; j < NSLOT; ++j) {
            acc_ws[wv][j * 4 + 0] = ar[j];
            acc_ws[wv][j * 4 + 1] = a2[j];
            acc_ws[wv][j * 4 + 2] = ao[j];
            acc_ws[wv][j * 4 + 3] = ac[j];
        }
    }
    __syncthreads();
    if (tid < NG) {
        int j = tid - g0;
        float vr = ovf[tid * 4 + 0], v2 = ovf[tid * 4 + 1];
        float vo = ovf[tid * 4 + 2], vc = ovf[tid * 4 + 3];
        if (j >= 0 && j < NSLOT) {
            #pragma unroll
            for (int w = 0; w < 8; ++w) {
                vr += acc_ws[w][j * 4 + 0];
                v2 += acc_ws[w][j * 4 + 1];
                vo += acc_ws[w][j * 4 + 2];
                vc += acc_ws[w][j * 4 + 3];
            }
        }
        rsum_p[tid * PBLK + bid] = vr;
        r2_p[tid * PBLK + bid]   = v2;
        ov_p[tid * PBLK + bid]   = vo;
        cnt_p[tid * PBLK + bid]  = vc;
    }
}

// ---------------- fallback path (gather + LDS atomics) ----------------

__global__ __launch_bounds__(FB_BLK) void pass1_fb(
    const int* __restrict__ idx0, const int* __restrict__ idx1,
    const float* __restrict__ attr, const float4* __restrict__ A,
    float* __restrict__ rsum_p, float* __restrict__ r2_p,
    float* __restrict__ ov_p, float* __restrict__ cnt_p) {
    __shared__ float sb_r[NCOPY*CSTR], sb_r2[NCOPY*CSTR], sb_ov[NCOPY*CSTR], sb_c[NCOPY*CSTR];
    int tid = threadIdx.x;
    for (int i = tid; i < NCOPY*CSTR; i += FB_BLK) { sb_r[i]=0.f; sb_r2[i]=0.f; sb_ov[i]=0.f; sb_c[i]=0.f; }
    __syncthreads();
    const int copy_off = (tid & (NCOPY - 1)) * CSTR;
    const int4* v0 = (const int4*)idx0;
    const int4* v1 = (const int4*)idx1;
    const float4* va = (const float4*)attr;
    const int gid = blockIdx.x * FB_BLK + tid;
    const int GRID = FB_NBLK * FB_BLK;
    for (int it = 0; it < 4; ++it) {
        int i = gid + it * GRID;
        int4 s4 = v0[i]; int4 t4 = v1[i]; float4 d4 = va[i];
        int   ss[4] = {s4.x, s4.y, s4.z, s4.w};
        int   tt[4] = {t4.x, t4.y, t4.z, t4.w};
        float dd[4] = {d4.x, d4.y, d4.z, d4.w};
        #pragma unroll
        for (int k = 0; k < 4; ++k) {
            float4 as_ = A[ss[k]], at_ = A[tt[k]];
            int g = (int)(__float_as_uint(as_.z) & 63u);
            int b = copy_off + g;
            float dx = as_.x - at_.x, dy = as_.y - at_.y;
            float eu = sqrtf(dx * dx + dy * dy);
            float r = eu / dd[k];
            atomicAdd(&sb_r[b], r);
            atomicAdd(&sb_r2[b], r * r);
            float ox = fmaxf((as_.z + at_.z) * 0.5f - fabsf(dx), 0.f);
            float oy = fmaxf((as_.w + at_.w) * 0.5f - fabsf(dy), 0.f);
            atomicAdd(&sb_ov[b], (ox * oy) / (as_.z + as_.w + at_.z + at_.w));
            atomicAdd(&sb_c[b], 1.f);
        }
    }
    __syncthreads();
    if (tid < NG) {
        float r = 0.f, r2 = 0.f, ov = 0.f, c = 0.f;
        #pragma unroll
        for (int cp = 0; cp < NCOPY; ++cp) {
            int b = cp * CSTR + tid;
            r += sb_r[b]; r2 += sb_r2[b]; ov += sb_ov[b]; c += sb_c[b];
        }
        int o = tid * FB_NBLK + blockIdx.x;
        rsum_p[o] = r; r2_p[o] = r2; ov_p[o] = ov; cnt_p[o] = c;
    }
}

// ---------------- host ----------------

extern "C" void kernel_launch(void* const* d_in, const int* in_sizes, int n_in,
                              void* d_out, int out_size, void* d_ws, size_t ws_size,
                              hipStream_t stream) {
    const float* node_pos   = (const float*)d_in[0];
    const float* node_sizes = (const float*)d_in[1];
    const float* attr       = (const float*)d_in[2];
    const int*   eidx       = (const int*)d_in[3];
    const int*   batch      = (const int*)d_in[4];
    float* out = (float*)d_out;
    unsigned* ws = (unsigned*)d_ws;
    const int* idx0 = eidx;
    const int* idx1 = eidx + NE;

    // sorted-path layout (u32 units)
    const size_t o_srt    = 0;                               // 2*NE
    const size_t o_rel    = o_srt + (size_t)2 * NE;          // NBUCK*SBLK
    const size_t o_rowtot = o_rel + (size_t)NBUCK * SBLK;
    const size_t o_gbase  = o_rowtot + 1024;
    const size_t o_A      = o_gbase + 1028;                  // 16B-aligned
    const size_t o_part   = o_A + (size_t)4 * NN;
    const size_t o_small  = o_part + (size_t)4 * NG * PBLK;
    const size_t need     = (o_small + 256) * 4;

    if (ws_size >= need) {
        unsigned* rel    = ws + o_rel;
        unsigned* rowtot = ws + o_rowtot;
        unsigned* gbase  = ws + o_gbase;
        uvec2*    srt    = (uvec2*)(ws + o_srt);
        float4* A = (float4*)(ws + o_A);
        float* rsum_p = (float*)(ws + o_part);
        float* r2_p   = rsum_p + NG * PBLK;
        float* ov_p   = r2_p + NG * PBLK;
        float* cnt_p  = ov_p + NG * PBLK;
        float* comb   = (float*)(ws + o_small);

        build_A_kernel<<<NN / 256, 256, 0, stream>>>((const float2*)node_pos,
                                                     (const float2*)node_sizes, batch, A);
        khist<<<SBLK, 512, 0, stream>>>(idx0, idx1, rel);
        kscan16<<<NBUCK / 16, 512, 0, stream>>>(rel, rowtot);
        kscan_base<<<1, 1024, 0, stream>>>(rowtot, gbase);
        kscatter<<<SBLK, 1024, 0, stream>>>(idx0, idx1, attr, rel, gbase, srt);
        kproc1<<<PBLK, 512, 0, stream>>>(srt, gbase, A, rsum_p, r2_p, ov_p, cnt_p);
        reduce_final1<<<NG, 256, 0, stream>>>(rsum_p, r2_p, ov_p, cnt_p, batch, PBLK, comb);
        final_kernel<<<1, 64, 0, stream>>>(comb, out);
    } else {
        // fallback: gather path (~6.3 MB ws)
        const int P = NG * FB_NBLK;
        float* rsum_p = (float*)ws;
        float* r2_p   = rsum_p + P;
        float* ov_p   = r2_p + P;
        float* cnt_p  = ov_p + P;
        float* comb   = cnt_p + P;
        float4* A = (float4*)(comb + 64);

        build_A_kernel<<<NN / 256, 256, 0, stream>>>((const float2*)node_pos,
                                                     (const float2*)node_sizes, batch, A);
        pass1_fb<<<FB_NBLK, FB_BLK, 0, stream>>>(idx0, idx1, attr, A, rsum_p, r2_p, ov_p, cnt_p);
        reduce_final1<<<NG, 256, 0, stream>>>(rsum_p, r2_p, ov_p, cnt_p, batch, FB_NBLK, comb);
        final_kernel<<<1, 64, 0, stream>>>(comb, out);
    }
}

// Round 7
// 140.685 us; speedup vs baseline: 1.8466x; 1.0455x over previous
//
#include <hip/hip_runtime.h>

#define NN 131072
#define NE 8388608
#define NG 64
#define TSH 12
#define TSZ 4096          // nodes per tile
#define NTILE 32
#define NBUCK 1024        // NTILE*NTILE
#define SBLK 512          // hist/scatter blocks
#define CHUNK 16384       // edges per hist/scatter block (NE/SBLK)
#define PBLK 1024         // process blocks (= NBUCK)
#define BLKP 1024         // kproc1 block size (16 waves -> 50% occ cap at 1 block/CU)
#define NSLOT 6           // max graphs spanned by one 4096-node tile (sorted batch)
#define NCOPY 4
#define CSTR 68
// fallback geometry
#define FB_NBLK 2048
#define FB_BLK 256

typedef unsigned uvec2 __attribute__((ext_vector_type(2)));

__device__ __forceinline__ uvec2 ldnt_u2(const uvec2* p) {
    return __builtin_nontemporal_load(p);
}

__device__ __forceinline__ float frcp(float x) { return __builtin_amdgcn_rcpf(x); }
__device__ __forceinline__ float fsqrt_fast(float x) { return __builtin_amdgcn_sqrtf(x); }

__device__ __forceinline__ int lower_bound_dev(const int* a, int n, int v) {
    int lo = 0, hi = n;
    while (lo < hi) { int mid = (lo + hi) >> 1; if (a[mid] < v) lo = mid + 1; else hi = mid; }
    return lo;
}

// ---------------- shared small kernels ----------------

// Pack {pos.x, pos.y, size.x (g in low 6 mantissa bits), size.y} per node.
__global__ void build_A_kernel(const float2* __restrict__ pos, const float2* __restrict__ sz,
                               const int* __restrict__ batch, float4* __restrict__ A) {
    int n = blockIdx.x * blockDim.x + threadIdx.x;
    if (n < NN) {
        float2 p = pos[n]; float2 s = sz[n];
        unsigned u = __float_as_uint(s.x);
        u = (u & ~63u) | (unsigned)batch[n];
        A[n] = make_float4(p.x, p.y, __uint_as_float(u), s.y);
    }
}

// Final per-graph math using the identity graph_stress = cnt - S1^2/S2
// (scale = S2/S1; edge_stress = (r/scale - 1)^2 sums to cnt - S1^2/S2).
__global__ void reduce_final1(const float* __restrict__ rsum_p, const float* __restrict__ r2_p,
                              const float* __restrict__ ov_p, const float* __restrict__ cnt_p,
                              const int* __restrict__ batch, int nblk,
                              float* __restrict__ comb) {
    int g = blockIdx.x, tid = threadIdx.x;
    float a = 0.f, b = 0.f, c = 0.f, d = 0.f;
    for (int i = tid; i < nblk; i += 256) {
        a += rsum_p[g * nblk + i];
        b += r2_p[g * nblk + i];
        c += ov_p[g * nblk + i];
        d += cnt_p[g * nblk + i];
    }
    __shared__ float sa[256], sb[256], sc[256], sd[256];
    sa[tid] = a; sb[tid] = b; sc[tid] = c; sd[tid] = d;
    __syncthreads();
    for (int s = 128; s > 0; s >>= 1) {
        if (tid < s) { sa[tid] += sa[tid+s]; sb[tid] += sb[tid+s]; sc[tid] += sc[tid+s]; sd[tid] += sd[tid+s]; }
        __syncthreads();
    }
    if (tid == 0) {
        float S1 = sa[0], S2 = sb[0], Sov = sc[0], cnt = sd[0];
        int lo = lower_bound_dev(batch, NN, g);
        int hi = lower_bound_dev(batch, NN, g + 1);
        float n = (float)(hi - lo);
        float stress = cnt - (S1 * S1) / S2;
        comb[g] = stress / (n * n) + Sov / fmaxf(cnt, 1.f);
    }
}

__global__ void final_kernel(const float* __restrict__ comb, float* __restrict__ out) {
    float v = comb[threadIdx.x];
    #pragma unroll
    for (int off = 32; off > 0; off >>= 1) v += __shfl_down(v, off);
    if (threadIdx.x == 0) out[0] = v * (1.0f / 64.0f);
}

// ---------------- sorted path ----------------

// counts layout: counts[blk * NBUCK + j]  (block-major, coalesced here and in kscatter)
__global__ __launch_bounds__(512) void khist(const int* __restrict__ idx0, const int* __restrict__ idx1,
                                             unsigned* __restrict__ counts) {
    __shared__ unsigned hist[2 * 1032];
    int tid = threadIdx.x, blk = blockIdx.x;
    for (int i = tid; i < 2 * 1032; i += 512) hist[i] = 0;
    __syncthreads();
    const int co = (tid & 1) * 1032;
    const int4* v0 = (const int4*)idx0 + blk * (CHUNK / 4);
    const int4* v1 = (const int4*)idx1 + blk * (CHUNK / 4);
    for (int i = tid; i < CHUNK / 4; i += 512) {
        int4 s4 = v0[i]; int4 t4 = v1[i];
        atomicAdd(&hist[co + (((s4.x >> TSH) << 5) | (t4.x >> TSH))], 1u);
        atomicAdd(&hist[co + (((s4.y >> TSH) << 5) | (t4.y >> TSH))], 1u);
        atomicAdd(&hist[co + (((s4.z >> TSH) << 5) | (t4.z >> TSH))], 1u);
        atomicAdd(&hist[co + (((s4.w >> TSH) << 5) | (t4.w >> TSH))], 1u);
    }
    __syncthreads();
    for (int j = tid; j < NBUCK; j += 512)
        counts[(size_t)blk * NBUCK + j] = hist[j] + hist[1032 + j];
}

// Per-bucket exclusive scan across blocks, 16 buckets per block.
__global__ __launch_bounds__(512) void kscan16(unsigned* __restrict__ counts,
                                               unsigned* __restrict__ rowtot) {
    const int j0 = blockIdx.x * 16;
    const int tid = threadIdx.x;               // = source block index
    const int ln = tid & 63, wv = tid >> 6;
    unsigned* base = counts + (size_t)tid * NBUCK + j0;
    uint4 q0 = *(const uint4*)(base);
    uint4 q1 = *(const uint4*)(base + 4);
    uint4 q2 = *(const uint4*)(base + 8);
    uint4 q3 = *(const uint4*)(base + 12);
    unsigned v[16] = {q0.x,q0.y,q0.z,q0.w, q1.x,q1.y,q1.z,q1.w,
                      q2.x,q2.y,q2.z,q2.w, q3.x,q3.y,q3.z,q3.w};
    unsigned ex[16];
    __shared__ unsigned wpart[8];
    #pragma unroll
    for (int k = 0; k < 16; ++k) {
        unsigned x = v[k];
        #pragma unroll
        for (int off = 1; off < 64; off <<= 1) {
            unsigned y = __shfl_up(x, off);
            if (ln >= off) x += y;
        }
        if (ln == 63) wpart[wv] = x;
        __syncthreads();
        unsigned wb = 0;
        for (int w = 0; w < 8; ++w) wb += (w < wv) ? wpart[w] : 0;
        ex[k] = wb + x - v[k];
        if (tid == 511) rowtot[j0 + k] = wb + x;
        __syncthreads();
    }
    *(uint4*)(base)      = make_uint4(ex[0], ex[1], ex[2], ex[3]);
    *(uint4*)(base + 4)  = make_uint4(ex[4], ex[5], ex[6], ex[7]);
    *(uint4*)(base + 8)  = make_uint4(ex[8], ex[9], ex[10], ex[11]);
    *(uint4*)(base + 12) = make_uint4(ex[12], ex[13], ex[14], ex[15]);
}

__global__ __launch_bounds__(1024) void kscan_base(const unsigned* __restrict__ rowtot,
                                                   unsigned* __restrict__ gbase) {
    int tid = threadIdx.x;
    __shared__ unsigned sc[1024];
    unsigned v = rowtot[tid];
    sc[tid] = v; __syncthreads();
    for (int off = 1; off < 1024; off <<= 1) {
        unsigned w = (tid >= off) ? sc[tid - off] : 0; __syncthreads();
        sc[tid] += w; __syncthreads();
    }
    gbase[tid] = sc[tid] - v;
    if (tid == 1023) gbase[1024] = sc[1023];
}

// LDS-staged scatter into bucket-sorted order. 8B records:
//   rx = s_local(12) | t_local(12)<<12 | (bucket&255)<<24
//   ry = (d_bits & ~3) | bucket>>8      (2 low mantissa bits of d stolen;
//        rel err 2.4e-7, cancels in S1^2/S2 since it's a per-edge scale on r)
__global__ __launch_bounds__(1024) void kscatter(const int* __restrict__ idx0, const int* __restrict__ idx1,
                                                 const float* __restrict__ attr,
                                                 const unsigned* __restrict__ rel,
                                                 const unsigned* __restrict__ gbase,
                                                 uvec2* __restrict__ srt) {
    __shared__ uvec2 pay[CHUNK];                       // 128 KB
    __shared__ unsigned hist[NBUCK], loc[NBUCK], wbase[NBUCK];
    __shared__ unsigned wpart[16];
    int tid = threadIdx.x, blk = blockIdx.x;
    const int ln = tid & 63, wv = tid >> 6;
    hist[tid] = 0;
    __syncthreads();
    unsigned rx[16], ry[16];
    const int4* v0 = (const int4*)idx0 + blk * (CHUNK / 4);
    const int4* v1 = (const int4*)idx1 + blk * (CHUNK / 4);
    const int4* va = (const int4*)attr + blk * (CHUNK / 4);
    #pragma unroll
    for (int k = 0; k < 4; ++k) {
        int i = tid + k * 1024;
        int4 s4 = v0[i]; int4 t4 = v1[i]; int4 d4 = va[i];
        unsigned ss[4] = {(unsigned)s4.x, (unsigned)s4.y, (unsigned)s4.z, (unsigned)s4.w};
        unsigned tt[4] = {(unsigned)t4.x, (unsigned)t4.y, (unsigned)t4.z, (unsigned)t4.w};
        unsigned dd[4] = {(unsigned)d4.x, (unsigned)d4.y, (unsigned)d4.z, (unsigned)d4.w};
        #pragma unroll
        for (int m = 0; m < 4; ++m) {
            unsigned j = ((ss[m] >> TSH) << 5) | (tt[m] >> TSH);
            rx[4*k+m] = (ss[m] & (TSZ-1)) | ((tt[m] & (TSZ-1)) << 12) | ((j & 255u) << 24);
            ry[4*k+m] = (dd[m] & ~3u) | (j >> 8);
            atomicAdd(&hist[j], 1u);
        }
    }
    __syncthreads();
    unsigned h = hist[tid];
    unsigned x = h;
    #pragma unroll
    for (int off = 1; off < 64; off <<= 1) {
        unsigned y = __shfl_up(x, off);
        if (ln >= off) x += y;
    }
    if (ln == 63) wpart[wv] = x;
    __syncthreads();
    unsigned wb = 0;
    for (int w = 0; w < 16; ++w) wb += (w < wv) ? wpart[w] : 0;
    unsigned ex = wb + x - h;
    loc[tid]   = ex;
    wbase[tid] = gbase[tid] + rel[(size_t)blk * NBUCK + tid] - ex;
    __syncthreads();
    #pragma unroll
    for (int k = 0; k < 16; ++k) {
        unsigned j = ((rx[k] >> 24) & 255u) | ((ry[k] & 3u) << 8);
        unsigned p = atomicAdd(&loc[j], 1u);
        uvec2 r; r.x = rx[k]; r.y = ry[k];
        pay[p] = r;
    }
    __syncthreads();
    for (int p = tid; p < CHUNK; p += 1024) {
        uvec2 r = pay[p];
        unsigned j = ((r.x >> 24) & 255u) | ((r.y & 3u) << 8);
        srt[wbase[j] + p] = r;
    }
}

// Process pass: both tiles in LDS, per-lane register-slot accumulation.
// 1024 threads: LDS caps at 1 block/CU regardless, so 16 waves doubles occupancy.
__global__ __launch_bounds__(BLKP) void kproc1(const uvec2* __restrict__ srt,
                                               const unsigned* __restrict__ gbase,
                                               const float4* __restrict__ A,
                                               float* __restrict__ rsum_p, float* __restrict__ r2_p,
                                               float* __restrict__ ov_p, float* __restrict__ cnt_p) {
    __shared__ float4 tS[TSZ], tT[TSZ];
    __shared__ float acc_ws[16][NSLOT * 4];
    __shared__ float ovf[NG * 4];            // overflow path: never taken in practice
    int tid = threadIdx.x, bid = blockIdx.x;
    const float4* As = A + (bid >> 5) * TSZ;
    const float4* At = A + (bid & 31) * TSZ;
    for (int i = tid; i < TSZ; i += BLKP) { tS[i] = As[i]; tT[i] = At[i]; }
    for (int i = tid; i < NG * 4; i += BLKP) ovf[i] = 0.f;
    __syncthreads();
    const int g0 = (int)(__float_as_uint(tS[0].z) & 63u);
    float ar[NSLOT], a2[NSLOT], ao[NSLOT], ac[NSLOT];
    #pragma unroll
    for (int j = 0; j < NSLOT; ++j) { ar[j] = 0.f; a2[j] = 0.f; ao[j] = 0.f; ac[j] = 0.f; }
    const int lo = (int)gbase[bid], hi = (int)gbase[bid + 1];
    int i = lo + tid;
    uvec2 rec;
    if (i < hi) rec = ldnt_u2(srt + i);
    while (i < hi) {
        int inext = i + BLKP;
        uvec2 nrec;
        if (inext < hi) nrec = ldnt_u2(srt + inext);   // in flight during compute
        float d = __uint_as_float(rec.y & ~3u);
        float4 a = tS[rec.x & (TSZ - 1)];
        float4 b = tT[(rec.x >> 12) & (TSZ - 1)];
        int dg = (int)(__float_as_uint(a.z) & 63u) - g0;   // >= 0 (batch sorted)
        float dx = a.x - b.x, dy = a.y - b.y;
        float eu = fsqrt_fast(dx * dx + dy * dy);
        float r = eu * frcp(d);
        float r2 = r * r;
        float ox = fmaxf((a.z + b.z) * 0.5f - fabsf(dx), 0.f);
        float oy = fmaxf((a.w + b.w) * 0.5f - fabsf(dy), 0.f);
        float nov = (ox * oy) * frcp(a.z + a.w + b.z + b.w);
        if (__builtin_expect(dg >= NSLOT, 0)) {
            int gg = g0 + dg;
            atomicAdd(&ovf[gg * 4 + 0], r);
            atomicAdd(&ovf[gg * 4 + 1], r2);
            atomicAdd(&ovf[gg * 4 + 2], nov);
            atomicAdd(&ovf[gg * 4 + 3], 1.f);
        } else {
            #pragma unroll
            for (int j = 0; j < NSLOT; ++j) {
                float m = (dg == j) ? 1.f : 0.f;
                ar[j] = fmaf(m, r, ar[j]);
                a2[j] = fmaf(m, r2, a2[j]);
                ao[j] = fmaf(m, nov, ao[j]);
                ac[j] += m;
            }
        }
        rec = nrec;
        i = inext;
    }
    #pragma unroll
    for (int j = 0; j < NSLOT; ++j) {
        for (int off = 1; off < 64; off <<= 1) {
            ar[j] += __shfl_xor(ar[j], off);
            a2[j] += __shfl_xor(a2[j], off);
            ao[j] += __shfl_xor(ao[j], off);
            ac[j] += __shfl_xor(ac[j], off);
        }
    }
    int wv = tid >> 6, ln = tid & 63;
    if (ln == 0) {
        #pragma unroll
        for (int j = 0; j < NSLOT; ++j) {
            acc_ws[wv][j * 4 + 0] = ar[j];
            acc_ws[wv][j * 4 + 1] = a2[j];
            acc_ws[wv][j * 4 + 2] = ao[j];
            acc_ws[wv][j * 4 + 3] = ac[j];
        }
    }
    __syncthreads();
    if (tid < NG) {
        int j = tid - g0;
        float vr = ovf[tid * 4 + 0], v2 = ovf[tid * 4 + 1];
        float vo = ovf[tid * 4 + 2], vc = ovf[tid * 4 + 3];
        if (j >= 0 && j < NSLOT) {
            #pragma unroll
            for (int w = 0; w < 16; ++w) {
                vr += acc_ws[w][j * 4 + 0];
                v2 += acc_ws[w][j * 4 + 1];
                vo += acc_ws[w][j * 4 + 2];
                vc += acc_ws[w][j * 4 + 3];
            }
        }
        rsum_p[tid * PBLK + bid] = vr;
        r2_p[tid * PBLK + bid]   = v2;
        ov_p[tid * PBLK + bid]   = vo;
        cnt_p[tid * PBLK + bid]  = vc;
    }
}

// ---------------- fallback path (gather + LDS atomics) ----------------

__global__ __launch_bounds__(FB_BLK) void pass1_fb(
    const int* __restrict__ idx0, const int* __restrict__ idx1,
    const float* __restrict__ attr, const float4* __restrict__ A,
    float* __restrict__ rsum_p, float* __restrict__ r2_p,
    float* __restrict__ ov_p, float* __restrict__ cnt_p) {
    __shared__ float sb_r[NCOPY*CSTR], sb_r2[NCOPY*CSTR], sb_ov[NCOPY*CSTR], sb_c[NCOPY*CSTR];
    int tid = threadIdx.x;
    for (int i = tid; i < NCOPY*CSTR; i += FB_BLK) { sb_r[i]=0.f; sb_r2[i]=0.f; sb_ov[i]=0.f; sb_c[i]=0.f; }
    __syncthreads();
    const int copy_off = (tid & (NCOPY - 1)) * CSTR;
    const int4* v0 = (const int4*)idx0;
    const int4* v1 = (const int4*)idx1;
    const float4* va = (const float4*)attr;
    const int gid = blockIdx.x * FB_BLK + tid;
    const int GRID = FB_NBLK * FB_BLK;
    for (int it = 0; it < 4; ++it) {
        int i = gid + it * GRID;
        int4 s4 = v0[i]; int4 t4 = v1[i]; float4 d4 = va[i];
        int   ss[4] = {s4.x, s4.y, s4.z, s4.w};
        int   tt[4] = {t4.x, t4.y, t4.z, t4.w};
        float dd[4] = {d4.x, d4.y, d4.z, d4.w};
        #pragma unroll
        for (int k = 0; k < 4; ++k) {
            float4 as_ = A[ss[k]], at_ = A[tt[k]];
            int g = (int)(__float_as_uint(as_.z) & 63u);
            int b = copy_off + g;
            float dx = as_.x - at_.x, dy = as_.y - at_.y;
            float eu = fsqrt_fast(dx * dx + dy * dy);
            float r = eu * frcp(dd[k]);
            atomicAdd(&sb_r[b], r);
            atomicAdd(&sb_r2[b], r * r);
            float ox = fmaxf((as_.z + at_.z) * 0.5f - fabsf(dx), 0.f);
            float oy = fmaxf((as_.w + at_.w) * 0.5f - fabsf(dy), 0.f);
            atomicAdd(&sb_ov[b], (ox * oy) * frcp(as_.z + as_.w + at_.z + at_.w));
            atomicAdd(&sb_c[b], 1.f);
        }
    }
    __syncthreads();
    if (tid < NG) {
        float r = 0.f, r2 = 0.f, ov = 0.f, c = 0.f;
        #pragma unroll
        for (int cp = 0; cp < NCOPY; ++cp) {
            int b = cp * CSTR + tid;
            r += sb_r[b]; r2 += sb_r2[b]; ov += sb_ov[b]; c += sb_c[b];
        }
        int o = tid * FB_NBLK + blockIdx.x;
        rsum_p[o] = r; r2_p[o] = r2; ov_p[o] = ov; cnt_p[o] = c;
    }
}

// ---------------- host ----------------

extern "C" void kernel_launch(void* const* d_in, const int* in_sizes, int n_in,
                              void* d_out, int out_size, void* d_ws, size_t ws_size,
                              hipStream_t stream) {
    const float* node_pos   = (const float*)d_in[0];
    const float* node_sizes = (const float*)d_in[1];
    const float* attr       = (const float*)d_in[2];
    const int*   eidx       = (const int*)d_in[3];
    const int*   batch      = (const int*)d_in[4];
    float* out = (float*)d_out;
    unsigned* ws = (unsigned*)d_ws;
    const int* idx0 = eidx;
    const int* idx1 = eidx + NE;

    // sorted-path layout (u32 units)
    const size_t o_srt    = 0;                               // 2*NE
    const size_t o_rel    = o_srt + (size_t)2 * NE;          // NBUCK*SBLK
    const size_t o_rowtot = o_rel + (size_t)NBUCK * SBLK;
    const size_t o_gbase  = o_rowtot + 1024;
    const size_t o_A      = o_gbase + 1028;                  // 16B-aligned
    const size_t o_part   = o_A + (size_t)4 * NN;
    const size_t o_small  = o_part + (size_t)4 * NG * PBLK;
    const size_t need     = (o_small + 256) * 4;

    if (ws_size >= need) {
        unsigned* rel    = ws + o_rel;
        unsigned* rowtot = ws + o_rowtot;
        unsigned* gbase  = ws + o_gbase;
        uvec2*    srt    = (uvec2*)(ws + o_srt);
        float4* A = (float4*)(ws + o_A);
        float* rsum_p = (float*)(ws + o_part);
        float* r2_p   = rsum_p + NG * PBLK;
        float* ov_p   = r2_p + NG * PBLK;
        float* cnt_p  = ov_p + NG * PBLK;
        float* comb   = (float*)(ws + o_small);

        build_A_kernel<<<NN / 256, 256, 0, stream>>>((const float2*)node_pos,
                                                     (const float2*)node_sizes, batch, A);
        khist<<<SBLK, 512, 0, stream>>>(idx0, idx1, rel);
        kscan16<<<NBUCK / 16, 512, 0, stream>>>(rel, rowtot);
        kscan_base<<<1, 1024, 0, stream>>>(rowtot, gbase);
        kscatter<<<SBLK, 1024, 0, stream>>>(idx0, idx1, attr, rel, gbase, srt);
        kproc1<<<PBLK, BLKP, 0, stream>>>(srt, gbase, A, rsum_p, r2_p, ov_p, cnt_p);
        reduce_final1<<<NG, 256, 0, stream>>>(rsum_p, r2_p, ov_p, cnt_p, batch, PBLK, comb);
        final_kernel<<<1, 64, 0, stream>>>(comb, out);
    } else {
        // fallback: gather path (~6.3 MB ws)
        const int P = NG * FB_NBLK;
        float* rsum_p = (float*)ws;
        float* r2_p   = rsum_p + P;
        float* ov_p   = r2_p + P;
        float* cnt_p  = ov_p + P;
        float* comb   = cnt_p + P;
        float4* A = (float4*)(comb + 64);

        build_A_kernel<<<NN / 256, 256, 0, stream>>>((const float2*)node_pos,
                                                     (const float2*)node_sizes, batch, A);
        pass1_fb<<<FB_NBLK, FB_BLK, 0, stream>>>(idx0, idx1, attr, A, rsum_p, r2_p, ov_p, cnt_p);
        reduce_final1<<<NG, 256, 0, stream>>>(rsum_p, r2_p, ov_p, cnt_p, batch, FB_NBLK, comb);
        final_kernel<<<1, 64, 0, stream>>>(comb, out);
    }
}

// Round 8
// 130.179 us; speedup vs baseline: 1.9957x; 1.0807x over previous
//
#include <hip/hip_runtime.h>

#define NN 131072
#define NE 8388608
#define NG 64
#define TSH 12
#define TSZ 4096          // nodes per tile
#define NTILE 32
#define NBUCK 1024        // NTILE*NTILE
#define SBLK 512          // hist/scatter blocks
#define CHUNK 16384       // edges per hist/scatter block (NE/SBLK)
#define PBLK 1024         // process blocks (= NBUCK)
#define BLKP 1024         // kproc1 block size (16 waves)
#define NSLOT 4           // graphs spanned by a 4096-node tile (2048±45/graph -> 3, rarely 4)
#define KPF 8             // prefetch depth = avg edges/thread in a bucket
#define NCOPY 4
#define CSTR 68
// fallback geometry
#define FB_NBLK 2048
#define FB_BLK 256

typedef unsigned uvec2 __attribute__((ext_vector_type(2)));

__device__ __forceinline__ uvec2 ldnt_u2(const uvec2* p) {
    return __builtin_nontemporal_load(p);
}

__device__ __forceinline__ float frcp(float x) { return __builtin_amdgcn_rcpf(x); }
__device__ __forceinline__ float fsqrt_fast(float x) { return __builtin_amdgcn_sqrtf(x); }

__device__ __forceinline__ int lower_bound_dev(const int* a, int n, int v) {
    int lo = 0, hi = n;
    while (lo < hi) { int mid = (lo + hi) >> 1; if (a[mid] < v) lo = mid + 1; else hi = mid; }
    return lo;
}

// ---------------- shared small kernels ----------------

// Pack {pos.x, pos.y, size.x (g in low 6 mantissa bits), size.y} per node.
__global__ void build_A_kernel(const float2* __restrict__ pos, const float2* __restrict__ sz,
                               const int* __restrict__ batch, float4* __restrict__ A) {
    int n = blockIdx.x * blockDim.x + threadIdx.x;
    if (n < NN) {
        float2 p = pos[n]; float2 s = sz[n];
        unsigned u = __float_as_uint(s.x);
        u = (u & ~63u) | (unsigned)batch[n];
        A[n] = make_float4(p.x, p.y, __uint_as_float(u), s.y);
    }
}

// Final per-graph math using the identity graph_stress = cnt - S1^2/S2
// (scale = S2/S1; edge_stress = (r/scale - 1)^2 sums to cnt - S1^2/S2).
__global__ void reduce_final1(const float* __restrict__ rsum_p, const float* __restrict__ r2_p,
                              const float* __restrict__ ov_p, const float* __restrict__ cnt_p,
                              const int* __restrict__ batch, int nblk,
                              float* __restrict__ comb) {
    int g = blockIdx.x, tid = threadIdx.x;
    float a = 0.f, b = 0.f, c = 0.f, d = 0.f;
    for (int i = tid; i < nblk; i += 256) {
        a += rsum_p[g * nblk + i];
        b += r2_p[g * nblk + i];
        c += ov_p[g * nblk + i];
        d += cnt_p[g * nblk + i];
    }
    __shared__ float sa[256], sb[256], sc[256], sd[256];
    sa[tid] = a; sb[tid] = b; sc[tid] = c; sd[tid] = d;
    __syncthreads();
    for (int s = 128; s > 0; s >>= 1) {
        if (tid < s) { sa[tid] += sa[tid+s]; sb[tid] += sb[tid+s]; sc[tid] += sc[tid+s]; sd[tid] += sd[tid+s]; }
        __syncthreads();
    }
    if (tid == 0) {
        float S1 = sa[0], S2 = sb[0], Sov = sc[0], cnt = sd[0];
        int lo = lower_bound_dev(batch, NN, g);
        int hi = lower_bound_dev(batch, NN, g + 1);
        float n = (float)(hi - lo);
        float stress = cnt - (S1 * S1) / S2;
        comb[g] = stress / (n * n) + Sov / fmaxf(cnt, 1.f);
    }
}

__global__ void final_kernel(const float* __restrict__ comb, float* __restrict__ out) {
    float v = comb[threadIdx.x];
    #pragma unroll
    for (int off = 32; off > 0; off >>= 1) v += __shfl_down(v, off);
    if (threadIdx.x == 0) out[0] = v * (1.0f / 64.0f);
}

// ---------------- sorted path ----------------

// counts layout: counts[blk * NBUCK + j]  (block-major, coalesced here and in kscatter)
__global__ __launch_bounds__(512) void khist(const int* __restrict__ idx0, const int* __restrict__ idx1,
                                             unsigned* __restrict__ counts) {
    __shared__ unsigned hist[2 * 1032];
    int tid = threadIdx.x, blk = blockIdx.x;
    for (int i = tid; i < 2 * 1032; i += 512) hist[i] = 0;
    __syncthreads();
    const int co = (tid & 1) * 1032;
    const int4* v0 = (const int4*)idx0 + blk * (CHUNK / 4);
    const int4* v1 = (const int4*)idx1 + blk * (CHUNK / 4);
    for (int i = tid; i < CHUNK / 4; i += 512) {
        int4 s4 = v0[i]; int4 t4 = v1[i];
        atomicAdd(&hist[co + (((s4.x >> TSH) << 5) | (t4.x >> TSH))], 1u);
        atomicAdd(&hist[co + (((s4.y >> TSH) << 5) | (t4.y >> TSH))], 1u);
        atomicAdd(&hist[co + (((s4.z >> TSH) << 5) | (t4.z >> TSH))], 1u);
        atomicAdd(&hist[co + (((s4.w >> TSH) << 5) | (t4.w >> TSH))], 1u);
    }
    __syncthreads();
    for (int j = tid; j < NBUCK; j += 512)
        counts[(size_t)blk * NBUCK + j] = hist[j] + hist[1032 + j];
}

// Per-bucket exclusive scan across blocks, 16 buckets per block.
__global__ __launch_bounds__(512) void kscan16(unsigned* __restrict__ counts,
                                               unsigned* __restrict__ rowtot) {
    const int j0 = blockIdx.x * 16;
    const int tid = threadIdx.x;               // = source block index
    const int ln = tid & 63, wv = tid >> 6;
    unsigned* base = counts + (size_t)tid * NBUCK + j0;
    uint4 q0 = *(const uint4*)(base);
    uint4 q1 = *(const uint4*)(base + 4);
    uint4 q2 = *(const uint4*)(base + 8);
    uint4 q3 = *(const uint4*)(base + 12);
    unsigned v[16] = {q0.x,q0.y,q0.z,q0.w, q1.x,q1.y,q1.z,q1.w,
                      q2.x,q2.y,q2.z,q2.w, q3.x,q3.y,q3.z,q3.w};
    unsigned ex[16];
    __shared__ unsigned wpart[8];
    #pragma unroll
    for (int k = 0; k < 16; ++k) {
        unsigned x = v[k];
        #pragma unroll
        for (int off = 1; off < 64; off <<= 1) {
            unsigned y = __shfl_up(x, off);
            if (ln >= off) x += y;
        }
        if (ln == 63) wpart[wv] = x;
        __syncthreads();
        unsigned wb = 0;
        for (int w = 0; w < 8; ++w) wb += (w < wv) ? wpart[w] : 0;
        ex[k] = wb + x - v[k];
        if (tid == 511) rowtot[j0 + k] = wb + x;
        __syncthreads();
    }
    *(uint4*)(base)      = make_uint4(ex[0], ex[1], ex[2], ex[3]);
    *(uint4*)(base + 4)  = make_uint4(ex[4], ex[5], ex[6], ex[7]);
    *(uint4*)(base + 8)  = make_uint4(ex[8], ex[9], ex[10], ex[11]);
    *(uint4*)(base + 12) = make_uint4(ex[12], ex[13], ex[14], ex[15]);
}

__global__ __launch_bounds__(1024) void kscan_base(const unsigned* __restrict__ rowtot,
                                                   unsigned* __restrict__ gbase) {
    int tid = threadIdx.x;
    __shared__ unsigned sc[1024];
    unsigned v = rowtot[tid];
    sc[tid] = v; __syncthreads();
    for (int off = 1; off < 1024; off <<= 1) {
        unsigned w = (tid >= off) ? sc[tid - off] : 0; __syncthreads();
        sc[tid] += w; __syncthreads();
    }
    gbase[tid] = sc[tid] - v;
    if (tid == 1023) gbase[1024] = sc[1023];
}

// LDS-staged scatter into bucket-sorted order. 8B records:
//   rx = s_local(12) | t_local(12)<<12 | (bucket&255)<<24
//   ry = (d_bits & ~3) | bucket>>8      (2 low mantissa bits of d stolen;
//        rel err 2.4e-7, cancels in S1^2/S2 since it's a per-edge scale on r)
__global__ __launch_bounds__(1024) void kscatter(const int* __restrict__ idx0, const int* __restrict__ idx1,
                                                 const float* __restrict__ attr,
                                                 const unsigned* __restrict__ rel,
                                                 const unsigned* __restrict__ gbase,
                                                 uvec2* __restrict__ srt) {
    __shared__ uvec2 pay[CHUNK];                       // 128 KB
    __shared__ unsigned hist[NBUCK], loc[NBUCK], wbase[NBUCK];
    __shared__ unsigned wpart[16];
    int tid = threadIdx.x, blk = blockIdx.x;
    const int ln = tid & 63, wv = tid >> 6;
    hist[tid] = 0;
    __syncthreads();
    unsigned rx[16], ry[16];
    const int4* v0 = (const int4*)idx0 + blk * (CHUNK / 4);
    const int4* v1 = (const int4*)idx1 + blk * (CHUNK / 4);
    const int4* va = (const int4*)attr + blk * (CHUNK / 4);
    #pragma unroll
    for (int k = 0; k < 4; ++k) {
        int i = tid + k * 1024;
        int4 s4 = v0[i]; int4 t4 = v1[i]; int4 d4 = va[i];
        unsigned ss[4] = {(unsigned)s4.x, (unsigned)s4.y, (unsigned)s4.z, (unsigned)s4.w};
        unsigned tt[4] = {(unsigned)t4.x, (unsigned)t4.y, (unsigned)t4.z, (unsigned)t4.w};
        unsigned dd[4] = {(unsigned)d4.x, (unsigned)d4.y, (unsigned)d4.z, (unsigned)d4.w};
        #pragma unroll
        for (int m = 0; m < 4; ++m) {
            unsigned j = ((ss[m] >> TSH) << 5) | (tt[m] >> TSH);
            rx[4*k+m] = (ss[m] & (TSZ-1)) | ((tt[m] & (TSZ-1)) << 12) | ((j & 255u) << 24);
            ry[4*k+m] = (dd[m] & ~3u) | (j >> 8);
            atomicAdd(&hist[j], 1u);
        }
    }
    __syncthreads();
    unsigned h = hist[tid];
    unsigned x = h;
    #pragma unroll
    for (int off = 1; off < 64; off <<= 1) {
        unsigned y = __shfl_up(x, off);
        if (ln >= off) x += y;
    }
    if (ln == 63) wpart[wv] = x;
    __syncthreads();
    unsigned wb = 0;
    for (int w = 0; w < 16; ++w) wb += (w < wv) ? wpart[w] : 0;
    unsigned ex = wb + x - h;
    loc[tid]   = ex;
    wbase[tid] = gbase[tid] + rel[(size_t)blk * NBUCK + tid] - ex;
    __syncthreads();
    #pragma unroll
    for (int k = 0; k < 16; ++k) {
        unsigned j = ((rx[k] >> 24) & 255u) | ((ry[k] & 3u) << 8);
        unsigned p = atomicAdd(&loc[j], 1u);
        uvec2 r; r.x = rx[k]; r.y = ry[k];
        pay[p] = r;
    }
    __syncthreads();
    for (int p = tid; p < CHUNK; p += 1024) {
        uvec2 r = pay[p];
        unsigned j = ((r.x >> 24) & 255u) | ((r.y & 3u) << 8);
        srt[wbase[j] + p] = r;
    }
}

// Process pass: both tiles in LDS, per-lane register-slot accumulation,
// 8-deep double-buffered srt prefetch (a bucket is ~8 edges/thread).
__global__ __launch_bounds__(BLKP) void kproc1(const uvec2* __restrict__ srt,
                                               const unsigned* __restrict__ gbase,
                                               const float4* __restrict__ A,
                                               float* __restrict__ rsum_p, float* __restrict__ r2_p,
                                               float* __restrict__ ov_p, float* __restrict__ cnt_p) {
    __shared__ float4 tS[TSZ], tT[TSZ];
    __shared__ float acc_ws[16][NSLOT * 4];
    __shared__ float ovf[NG * 4];            // overflow path: ~never taken
    int tid = threadIdx.x, bid = blockIdx.x;
    const float4* As = A + (bid >> 5) * TSZ;
    const float4* At = A + (bid & 31) * TSZ;
    for (int i = tid; i < TSZ; i += BLKP) { tS[i] = As[i]; tT[i] = At[i]; }
    for (int i = tid; i < NG * 4; i += BLKP) ovf[i] = 0.f;
    __syncthreads();
    const int g0 = (int)(__float_as_uint(tS[0].z) & 63u);
    float ar[NSLOT], a2[NSLOT], ao[NSLOT], ac[NSLOT];
    #pragma unroll
    for (int j = 0; j < NSLOT; ++j) { ar[j] = 0.f; a2[j] = 0.f; ao[j] = 0.f; ac[j] = 0.f; }
    const int lo = (int)gbase[bid], hi = (int)gbase[bid + 1];
    const int i0 = lo + tid;
    uvec2 cur[KPF];
    #pragma unroll
    for (int k = 0; k < KPF; ++k) {
        int idx = i0 + k * BLKP;
        if (idx < hi) cur[k] = ldnt_u2(srt + idx);
    }
    for (int base = i0; base < hi; base += KPF * BLKP) {
        uvec2 nxt[KPF];
        #pragma unroll
        for (int k = 0; k < KPF; ++k) {
            int idx = base + KPF * BLKP + k * BLKP;
            if (idx < hi) nxt[k] = ldnt_u2(srt + idx);
        }
        #pragma unroll
        for (int k = 0; k < KPF; ++k) {
            int idx = base + k * BLKP;
            if (idx < hi) {
                uvec2 rec = cur[k];
                float d = __uint_as_float(rec.y & ~3u);
                float4 a = tS[rec.x & (TSZ - 1)];
                float4 b = tT[(rec.x >> 12) & (TSZ - 1)];
                int dg = (int)(__float_as_uint(a.z) & 63u) - g0;   // >= 0 (batch sorted)
                float dx = a.x - b.x, dy = a.y - b.y;
                float eu = fsqrt_fast(dx * dx + dy * dy);
                float r = eu * frcp(d);
                float r2 = r * r;
                float ox = fmaxf((a.z + b.z) * 0.5f - fabsf(dx), 0.f);
                float oy = fmaxf((a.w + b.w) * 0.5f - fabsf(dy), 0.f);
                float nov = (ox * oy) * frcp(a.z + a.w + b.z + b.w);
                if (__builtin_expect(dg >= NSLOT, 0)) {
                    int gg = g0 + dg;
                    atomicAdd(&ovf[gg * 4 + 0], r);
                    atomicAdd(&ovf[gg * 4 + 1], r2);
                    atomicAdd(&ovf[gg * 4 + 2], nov);
                    atomicAdd(&ovf[gg * 4 + 3], 1.f);
                } else {
                    #pragma unroll
                    for (int j = 0; j < NSLOT; ++j) {
                        float m = (dg == j) ? 1.f : 0.f;
                        ar[j] = fmaf(m, r, ar[j]);
                        a2[j] = fmaf(m, r2, a2[j]);
                        ao[j] = fmaf(m, nov, ao[j]);
                        ac[j] += m;
                    }
                }
            }
        }
        #pragma unroll
        for (int k = 0; k < KPF; ++k) cur[k] = nxt[k];
    }
    #pragma unroll
    for (int j = 0; j < NSLOT; ++j) {
        for (int off = 1; off < 64; off <<= 1) {
            ar[j] += __shfl_xor(ar[j], off);
            a2[j] += __shfl_xor(a2[j], off);
            ao[j] += __shfl_xor(ao[j], off);
            ac[j] += __shfl_xor(ac[j], off);
        }
    }
    int wv = tid >> 6, ln = tid & 63;
    if (ln == 0) {
        #pragma unroll
        for (int j = 0; j < NSLOT; ++j) {
            acc_ws[wv][j * 4 + 0] = ar[j];
            acc_ws[wv][j * 4 + 1] = a2[j];
            acc_ws[wv][j * 4 + 2] = ao[j];
            acc_ws[wv][j * 4 + 3] = ac[j];
        }
    }
    __syncthreads();
    if (tid < NG) {
        int j = tid - g0;
        float vr = ovf[tid * 4 + 0], v2 = ovf[tid * 4 + 1];
        float vo = ovf[tid * 4 + 2], vc = ovf[tid * 4 + 3];
        if (j >= 0 && j < NSLOT) {
            #pragma unroll
            for (int w = 0; w < 16; ++w) {
                vr += acc_ws[w][j * 4 + 0];
                v2 += acc_ws[w][j * 4 + 1];
                vo += acc_ws[w][j * 4 + 2];
                vc += acc_ws[w][j * 4 + 3];
            }
        }
        rsum_p[tid * PBLK + bid] = vr;
        r2_p[tid * PBLK + bid]   = v2;
        ov_p[tid * PBLK + bid]   = vo;
        cnt_p[tid * PBLK + bid]  = vc;
    }
}

// ---------------- fallback path (gather + LDS atomics) ----------------

__global__ __launch_bounds__(FB_BLK) void pass1_fb(
    const int* __restrict__ idx0, const int* __restrict__ idx1,
    const float* __restrict__ attr, const float4* __restrict__ A,
    float* __restrict__ rsum_p, float* __restrict__ r2_p,
    float* __restrict__ ov_p, float* __restrict__ cnt_p) {
    __shared__ float sb_r[NCOPY*CSTR], sb_r2[NCOPY*CSTR], sb_ov[NCOPY*CSTR], sb_c[NCOPY*CSTR];
    int tid = threadIdx.x;
    for (int i = tid; i < NCOPY*CSTR; i += FB_BLK) { sb_r[i]=0.f; sb_r2[i]=0.f; sb_ov[i]=0.f; sb_c[i]=0.f; }
    __syncthreads();
    const int copy_off = (tid & (NCOPY - 1)) * CSTR;
    const int4* v0 = (const int4*)idx0;
    const int4* v1 = (const int4*)idx1;
    const float4* va = (const float4*)attr;
    const int gid = blockIdx.x * FB_BLK + tid;
    const int GRID = FB_NBLK * FB_BLK;
    for (int it = 0; it < 4; ++it) {
        int i = gid + it * GRID;
        int4 s4 = v0[i]; int4 t4 = v1[i]; float4 d4 = va[i];
        int   ss[4] = {s4.x, s4.y, s4.z, s4.w};
        int   tt[4] = {t4.x, t4.y, t4.z, t4.w};
        float dd[4] = {d4.x, d4.y, d4.z, d4.w};
        #pragma unroll
        for (int k = 0; k < 4; ++k) {
            float4 as_ = A[ss[k]], at_ = A[tt[k]];
            int g = (int)(__float_as_uint(as_.z) & 63u);
            int b = copy_off + g;
            float dx = as_.x - at_.x, dy = as_.y - at_.y;
            float eu = fsqrt_fast(dx * dx + dy * dy);
            float r = eu * frcp(dd[k]);
            atomicAdd(&sb_r[b], r);
            atomicAdd(&sb_r2[b], r * r);
            float ox = fmaxf((as_.z + at_.z) * 0.5f - fabsf(dx), 0.f);
            float oy = fmaxf((as_.w + at_.w) * 0.5f - fabsf(dy), 0.f);
            atomicAdd(&sb_ov[b], (ox * oy) * frcp(as_.z + as_.w + at_.z + at_.w));
            atomicAdd(&sb_c[b], 1.f);
        }
    }
    __syncthreads();
    if (tid < NG) {
        float r = 0.f, r2 = 0.f, ov = 0.f, c = 0.f;
        #pragma unroll
        for (int cp = 0; cp < NCOPY; ++cp) {
            int b = cp * CSTR + tid;
            r += sb_r[b]; r2 += sb_r2[b]; ov += sb_ov[b]; c += sb_c[b];
        }
        int o = tid * FB_NBLK + blockIdx.x;
        rsum_p[o] = r; r2_p[o] = r2; ov_p[o] = ov; cnt_p[o] = c;
    }
}

// ---------------- host ----------------

extern "C" void kernel_launch(void* const* d_in, const int* in_sizes, int n_in,
                              void* d_out, int out_size, void* d_ws, size_t ws_size,
                              hipStream_t stream) {
    const float* node_pos   = (const float*)d_in[0];
    const float* node_sizes = (const float*)d_in[1];
    const float* attr       = (const float*)d_in[2];
    const int*   eidx       = (const int*)d_in[3];
    const int*   batch      = (const int*)d_in[4];
    float* out = (float*)d_out;
    unsigned* ws = (unsigned*)d_ws;
    const int* idx0 = eidx;
    const int* idx1 = eidx + NE;

    // sorted-path layout (u32 units)
    const size_t o_srt    = 0;                               // 2*NE
    const size_t o_rel    = o_srt + (size_t)2 * NE;          // NBUCK*SBLK
    const size_t o_rowtot = o_rel + (size_t)NBUCK * SBLK;
    const size_t o_gbase  = o_rowtot + 1024;
    const size_t o_A      = o_gbase + 1028;                  // 16B-aligned
    const size_t o_part   = o_A + (size_t)4 * NN;
    const size_t o_small  = o_part + (size_t)4 * NG * PBLK;
    const size_t need     = (o_small + 256) * 4;

    if (ws_size >= need) {
        unsigned* rel    = ws + o_rel;
        unsigned* rowtot = ws + o_rowtot;
        unsigned* gbase  = ws + o_gbase;
        uvec2*    srt    = (uvec2*)(ws + o_srt);
        float4* A = (float4*)(ws + o_A);
        float* rsum_p = (float*)(ws + o_part);
        float* r2_p   = rsum_p + NG * PBLK;
        float* ov_p   = r2_p + NG * PBLK;
        float* cnt_p  = ov_p + NG * PBLK;
        float* comb   = (float*)(ws + o_small);

        build_A_kernel<<<NN / 256, 256, 0, stream>>>((const float2*)node_pos,
                                                     (const float2*)node_sizes, batch, A);
        khist<<<SBLK, 512, 0, stream>>>(idx0, idx1, rel);
        kscan16<<<NBUCK / 16, 512, 0, stream>>>(rel, rowtot);
        kscan_base<<<1, 1024, 0, stream>>>(rowtot, gbase);
        kscatter<<<SBLK, 1024, 0, stream>>>(idx0, idx1, attr, rel, gbase, srt);
        kproc1<<<PBLK, BLKP, 0, stream>>>(srt, gbase, A, rsum_p, r2_p, ov_p, cnt_p);
        reduce_final1<<<NG, 256, 0, stream>>>(rsum_p, r2_p, ov_p, cnt_p, batch, PBLK, comb);
        final_kernel<<<1, 64, 0, stream>>>(comb, out);
    } else {
        // fallback: gather path (~6.3 MB ws)
        const int P = NG * FB_NBLK;
        float* rsum_p = (float*)ws;
        float* r2_p   = rsum_p + P;
        float* ov_p   = r2_p + P;
        float* cnt_p  = ov_p + P;
        float* comb   = cnt_p + P;
        float4* A = (float4*)(comb + 64);

        build_A_kernel<<<NN / 256, 256, 0, stream>>>((const float2*)node_pos,
                                                     (const float2*)node_sizes, batch, A);
        pass1_fb<<<FB_NBLK, FB_BLK, 0, stream>>>(idx0, idx1, attr, A, rsum_p, r2_p, ov_p, cnt_p);
        reduce_final1<<<NG, 256, 0, stream>>>(rsum_p, r2_p, ov_p, cnt_p, batch, FB_NBLK, comb);
        final_kernel<<<1, 64, 0, stream>>>(comb, out);
    }
}

// Round 9
// 128.043 us; speedup vs baseline: 2.0290x; 1.0167x over previous
//
#include <hip/hip_runtime.h>

#define NN 131072
#define NE 8388608
#define NG 64
#define TSH 12
#define TSZ 4096          // nodes per tile
#define NTILE 32
#define NBUCK 1024        // NTILE*NTILE
#define SBLK 512          // hist/scatter blocks
#define CHUNK 16384       // edges per hist/scatter block (NE/SBLK)
#define PBLK 1024         // process blocks (= NBUCK)
#define BLKP 1024         // kproc1 block size (16 waves)
#define NSLOT 4           // graphs spanned by a 4096-node tile (2048±45/graph -> 3, rarely 4)
#define KPF 8             // records per thread per group (avg bucket = 8192 = KPF*BLKP)
#define NCOPY 4
#define CSTR 68
// fallback geometry
#define FB_NBLK 2048
#define FB_BLK 256

typedef unsigned uvec2 __attribute__((ext_vector_type(2)));

__device__ __forceinline__ uvec2 ldnt_u2(const uvec2* p) {
    return __builtin_nontemporal_load(p);
}

__device__ __forceinline__ float frcp(float x) { return __builtin_amdgcn_rcpf(x); }
__device__ __forceinline__ float fsqrt_fast(float x) { return __builtin_amdgcn_sqrtf(x); }

__device__ __forceinline__ int lower_bound_dev(const int* a, int n, int v) {
    int lo = 0, hi = n;
    while (lo < hi) { int mid = (lo + hi) >> 1; if (a[mid] < v) lo = mid + 1; else hi = mid; }
    return lo;
}

// ---------------- shared small kernels ----------------

// Pack {pos.x, pos.y, size.x (g in low 6 mantissa bits), size.y} per node.
__global__ void build_A_kernel(const float2* __restrict__ pos, const float2* __restrict__ sz,
                               const int* __restrict__ batch, float4* __restrict__ A) {
    int n = blockIdx.x * blockDim.x + threadIdx.x;
    if (n < NN) {
        float2 p = pos[n]; float2 s = sz[n];
        unsigned u = __float_as_uint(s.x);
        u = (u & ~63u) | (unsigned)batch[n];
        A[n] = make_float4(p.x, p.y, __uint_as_float(u), s.y);
    }
}

// Final per-graph math using the identity graph_stress = cnt - S1^2/S2
// (scale = S2/S1; edge_stress = (r/scale - 1)^2 sums to cnt - S1^2/S2).
__global__ void reduce_final1(const float* __restrict__ rsum_p, const float* __restrict__ r2_p,
                              const float* __restrict__ ov_p, const float* __restrict__ cnt_p,
                              const int* __restrict__ batch, int nblk,
                              float* __restrict__ comb) {
    int g = blockIdx.x, tid = threadIdx.x;
    float a = 0.f, b = 0.f, c = 0.f, d = 0.f;
    for (int i = tid; i < nblk; i += 256) {
        a += rsum_p[g * nblk + i];
        b += r2_p[g * nblk + i];
        c += ov_p[g * nblk + i];
        d += cnt_p[g * nblk + i];
    }
    __shared__ float sa[256], sb[256], sc[256], sd[256];
    sa[tid] = a; sb[tid] = b; sc[tid] = c; sd[tid] = d;
    __syncthreads();
    for (int s = 128; s > 0; s >>= 1) {
        if (tid < s) { sa[tid] += sa[tid+s]; sb[tid] += sb[tid+s]; sc[tid] += sc[tid+s]; sd[tid] += sd[tid+s]; }
        __syncthreads();
    }
    if (tid == 0) {
        float S1 = sa[0], S2 = sb[0], Sov = sc[0], cnt = sd[0];
        int lo = lower_bound_dev(batch, NN, g);
        int hi = lower_bound_dev(batch, NN, g + 1);
        float n = (float)(hi - lo);
        float stress = cnt - (S1 * S1) / S2;
        comb[g] = stress / (n * n) + Sov / fmaxf(cnt, 1.f);
    }
}

__global__ void final_kernel(const float* __restrict__ comb, float* __restrict__ out) {
    float v = comb[threadIdx.x];
    #pragma unroll
    for (int off = 32; off > 0; off >>= 1) v += __shfl_down(v, off);
    if (threadIdx.x == 0) out[0] = v * (1.0f / 64.0f);
}

// ---------------- sorted path ----------------

// counts layout: counts[blk * NBUCK + j]  (block-major, coalesced here and in kscatter)
__global__ __launch_bounds__(512) void khist(const int* __restrict__ idx0, const int* __restrict__ idx1,
                                             unsigned* __restrict__ counts) {
    __shared__ unsigned hist[2 * 1032];
    int tid = threadIdx.x, blk = blockIdx.x;
    for (int i = tid; i < 2 * 1032; i += 512) hist[i] = 0;
    __syncthreads();
    const int co = (tid & 1) * 1032;
    const int4* v0 = (const int4*)idx0 + blk * (CHUNK / 4);
    const int4* v1 = (const int4*)idx1 + blk * (CHUNK / 4);
    for (int i = tid; i < CHUNK / 4; i += 512) {
        int4 s4 = v0[i]; int4 t4 = v1[i];
        atomicAdd(&hist[co + (((s4.x >> TSH) << 5) | (t4.x >> TSH))], 1u);
        atomicAdd(&hist[co + (((s4.y >> TSH) << 5) | (t4.y >> TSH))], 1u);
        atomicAdd(&hist[co + (((s4.z >> TSH) << 5) | (t4.z >> TSH))], 1u);
        atomicAdd(&hist[co + (((s4.w >> TSH) << 5) | (t4.w >> TSH))], 1u);
    }
    __syncthreads();
    for (int j = tid; j < NBUCK; j += 512)
        counts[(size_t)blk * NBUCK + j] = hist[j] + hist[1032 + j];
}

// Per-bucket exclusive scan across blocks, 16 buckets per block.
__global__ __launch_bounds__(512) void kscan16(unsigned* __restrict__ counts,
                                               unsigned* __restrict__ rowtot) {
    const int j0 = blockIdx.x * 16;
    const int tid = threadIdx.x;               // = source block index
    const int ln = tid & 63, wv = tid >> 6;
    unsigned* base = counts + (size_t)tid * NBUCK + j0;
    uint4 q0 = *(const uint4*)(base);
    uint4 q1 = *(const uint4*)(base + 4);
    uint4 q2 = *(const uint4*)(base + 8);
    uint4 q3 = *(const uint4*)(base + 12);
    unsigned v[16] = {q0.x,q0.y,q0.z,q0.w, q1.x,q1.y,q1.z,q1.w,
                      q2.x,q2.y,q2.z,q2.w, q3.x,q3.y,q3.z,q3.w};
    unsigned ex[16];
    __shared__ unsigned wpart[8];
    #pragma unroll
    for (int k = 0; k < 16; ++k) {
        unsigned x = v[k];
        #pragma unroll
        for (int off = 1; off < 64; off <<= 1) {
            unsigned y = __shfl_up(x, off);
            if (ln >= off) x += y;
        }
        if (ln == 63) wpart[wv] = x;
        __syncthreads();
        unsigned wb = 0;
        for (int w = 0; w < 8; ++w) wb += (w < wv) ? wpart[w] : 0;
        ex[k] = wb + x - v[k];
        if (tid == 511) rowtot[j0 + k] = wb + x;
        __syncthreads();
    }
    *(uint4*)(base)      = make_uint4(ex[0], ex[1], ex[2], ex[3]);
    *(uint4*)(base + 4)  = make_uint4(ex[4], ex[5], ex[6], ex[7]);
    *(uint4*)(base + 8)  = make_uint4(ex[8], ex[9], ex[10], ex[11]);
    *(uint4*)(base + 12) = make_uint4(ex[12], ex[13], ex[14], ex[15]);
}

__global__ __launch_bounds__(1024) void kscan_base(const unsigned* __restrict__ rowtot,
                                                   unsigned* __restrict__ gbase) {
    int tid = threadIdx.x;
    __shared__ unsigned sc[1024];
    unsigned v = rowtot[tid];
    sc[tid] = v; __syncthreads();
    for (int off = 1; off < 1024; off <<= 1) {
        unsigned w = (tid >= off) ? sc[tid - off] : 0; __syncthreads();
        sc[tid] += w; __syncthreads();
    }
    gbase[tid] = sc[tid] - v;
    if (tid == 1023) gbase[1024] = sc[1023];
}

// LDS-staged scatter into bucket-sorted order. 8B records:
//   rx = s_local(12) | t_local(12)<<12 | (bucket&255)<<24
//   ry = (d_bits & ~3) | bucket>>8      (2 low mantissa bits of d stolen;
//        rel err 2.4e-7, cancels in S1^2/S2 since it's a per-edge scale on r)
__global__ __launch_bounds__(1024) void kscatter(const int* __restrict__ idx0, const int* __restrict__ idx1,
                                                 const float* __restrict__ attr,
                                                 const unsigned* __restrict__ rel,
                                                 const unsigned* __restrict__ gbase,
                                                 uvec2* __restrict__ srt) {
    __shared__ uvec2 pay[CHUNK];                       // 128 KB
    __shared__ unsigned hist[NBUCK], loc[NBUCK], wbase[NBUCK];
    __shared__ unsigned wpart[16];
    int tid = threadIdx.x, blk = blockIdx.x;
    const int ln = tid & 63, wv = tid >> 6;
    hist[tid] = 0;
    __syncthreads();
    unsigned rx[16], ry[16];
    const int4* v0 = (const int4*)idx0 + blk * (CHUNK / 4);
    const int4* v1 = (const int4*)idx1 + blk * (CHUNK / 4);
    const int4* va = (const int4*)attr + blk * (CHUNK / 4);
    #pragma unroll
    for (int k = 0; k < 4; ++k) {
        int i = tid + k * 1024;
        int4 s4 = v0[i]; int4 t4 = v1[i]; int4 d4 = va[i];
        unsigned ss[4] = {(unsigned)s4.x, (unsigned)s4.y, (unsigned)s4.z, (unsigned)s4.w};
        unsigned tt[4] = {(unsigned)t4.x, (unsigned)t4.y, (unsigned)t4.z, (unsigned)t4.w};
        unsigned dd[4] = {(unsigned)d4.x, (unsigned)d4.y, (unsigned)d4.z, (unsigned)d4.w};
        #pragma unroll
        for (int m = 0; m < 4; ++m) {
            unsigned j = ((ss[m] >> TSH) << 5) | (tt[m] >> TSH);
            rx[4*k+m] = (ss[m] & (TSZ-1)) | ((tt[m] & (TSZ-1)) << 12) | ((j & 255u) << 24);
            ry[4*k+m] = (dd[m] & ~3u) | (j >> 8);
            atomicAdd(&hist[j], 1u);
        }
    }
    __syncthreads();
    unsigned h = hist[tid];
    unsigned x = h;
    #pragma unroll
    for (int off = 1; off < 64; off <<= 1) {
        unsigned y = __shfl_up(x, off);
        if (ln >= off) x += y;
    }
    if (ln == 63) wpart[wv] = x;
    __syncthreads();
    unsigned wb = 0;
    for (int w = 0; w < 16; ++w) wb += (w < wv) ? wpart[w] : 0;
    unsigned ex = wb + x - h;
    loc[tid]   = ex;
    wbase[tid] = gbase[tid] + rel[(size_t)blk * NBUCK + tid] - ex;
    __syncthreads();
    #pragma unroll
    for (int k = 0; k < 16; ++k) {
        unsigned j = ((rx[k] >> 24) & 255u) | ((ry[k] & 3u) << 8);
        unsigned p = atomicAdd(&loc[j], 1u);
        uvec2 r; r.x = rx[k]; r.y = ry[k];
        pay[p] = r;
    }
    __syncthreads();
    for (int p = tid; p < CHUNK; p += 1024) {
        uvec2 r = pay[p];
        unsigned j = ((r.x >> 24) & 255u) | ((r.y & 3u) << 8);
        srt[wbase[j] + p] = r;
    }
}

// Process pass: both tiles in LDS, per-lane register-slot accumulation.
// Per 8-record group: two half-batches of 8 back-to-back ds_read_b128 into
// registers, then pure-VALU compute (hides LDS latency via ILP, not waves).
__global__ __launch_bounds__(BLKP) void kproc1(const uvec2* __restrict__ srt,
                                               const unsigned* __restrict__ gbase,
                                               const float4* __restrict__ A,
                                               float* __restrict__ rsum_p, float* __restrict__ r2_p,
                                               float* __restrict__ ov_p, float* __restrict__ cnt_p) {
    __shared__ float4 tS[TSZ], tT[TSZ];
    __shared__ float acc_ws[16][NSLOT * 4];
    __shared__ float ovf[NG * 4];            // overflow path: ~never taken
    int tid = threadIdx.x, bid = blockIdx.x;
    const float4* As = A + (bid >> 5) * TSZ;
    const float4* At = A + (bid & 31) * TSZ;
    for (int i = tid; i < TSZ; i += BLKP) { tS[i] = As[i]; tT[i] = At[i]; }
    for (int i = tid; i < NG * 4; i += BLKP) ovf[i] = 0.f;
    __syncthreads();
    const int g0 = (int)(__float_as_uint(tS[0].z) & 63u);
    float ar[NSLOT], a2[NSLOT], ao[NSLOT], ac[NSLOT];
    #pragma unroll
    for (int j = 0; j < NSLOT; ++j) { ar[j] = 0.f; a2[j] = 0.f; ao[j] = 0.f; ac[j] = 0.f; }
    const int lo = (int)gbase[bid], hi = (int)gbase[bid + 1];
    const int i0 = lo + tid;
    for (int base = i0; base < hi; base += KPF * BLKP) {
        uvec2 cur[KPF];
        #pragma unroll
        for (int k = 0; k < KPF; ++k) {
            int idx = base + k * BLKP;
            cur[k].x = 0u; cur[k].y = 0u;
            if (idx < hi) cur[k] = ldnt_u2(srt + idx);
        }
        #pragma unroll
        for (int h = 0; h < 2; ++h) {
            float4 av[4], bv[4];
            #pragma unroll
            for (int k2 = 0; k2 < 4; ++k2) {
                int k = h * 4 + k2;
                av[k2] = tS[cur[k].x & (TSZ - 1)];
                bv[k2] = tT[(cur[k].x >> 12) & (TSZ - 1)];
            }
            #pragma unroll
            for (int k2 = 0; k2 < 4; ++k2) {
                int k = h * 4 + k2;
                int idx = base + k * BLKP;
                if (idx < hi) {
                    float4 a = av[k2], b = bv[k2];
                    float d = __uint_as_float(cur[k].y & ~3u);
                    int dg = (int)(__float_as_uint(a.z) & 63u) - g0;   // >= 0 (batch sorted)
                    float dx = a.x - b.x, dy = a.y - b.y;
                    float eu = fsqrt_fast(dx * dx + dy * dy);
                    float r = eu * frcp(d);
                    float r2 = r * r;
                    float ox = fmaxf((a.z + b.z) * 0.5f - fabsf(dx), 0.f);
                    float oy = fmaxf((a.w + b.w) * 0.5f - fabsf(dy), 0.f);
                    float nov = (ox * oy) * frcp(a.z + a.w + b.z + b.w);
                    if (__builtin_expect(dg >= NSLOT, 0)) {
                        int gg = g0 + dg;
                        atomicAdd(&ovf[gg * 4 + 0], r);
                        atomicAdd(&ovf[gg * 4 + 1], r2);
                        atomicAdd(&ovf[gg * 4 + 2], nov);
                        atomicAdd(&ovf[gg * 4 + 3], 1.f);
                    } else {
                        #pragma unroll
                        for (int j = 0; j < NSLOT; ++j) {
                            float m = (dg == j) ? 1.f : 0.f;
                            ar[j] = fmaf(m, r, ar[j]);
                            a2[j] = fmaf(m, r2, a2[j]);
                            ao[j] = fmaf(m, nov, ao[j]);
                            ac[j] += m;
                        }
                    }
                }
            }
        }
    }
    #pragma unroll
    for (int j = 0; j < NSLOT; ++j) {
        for (int off = 1; off < 64; off <<= 1) {
            ar[j] += __shfl_xor(ar[j], off);
            a2[j] += __shfl_xor(a2[j], off);
            ao[j] += __shfl_xor(ao[j], off);
            ac[j] += __shfl_xor(ac[j], off);
        }
    }
    int wv = tid >> 6, ln = tid & 63;
    if (ln == 0) {
        #pragma unroll
        for (int j = 0; j < NSLOT; ++j) {
            acc_ws[wv][j * 4 + 0] = ar[j];
            acc_ws[wv][j * 4 + 1] = a2[j];
            acc_ws[wv][j * 4 + 2] = ao[j];
            acc_ws[wv][j * 4 + 3] = ac[j];
        }
    }
    __syncthreads();
    if (tid < NG) {
        int j = tid - g0;
        float vr = ovf[tid * 4 + 0], v2 = ovf[tid * 4 + 1];
        float vo = ovf[tid * 4 + 2], vc = ovf[tid * 4 + 3];
        if (j >= 0 && j < NSLOT) {
            #pragma unroll
            for (int w = 0; w < 16; ++w) {
                vr += acc_ws[w][j * 4 + 0];
                v2 += acc_ws[w][j * 4 + 1];
                vo += acc_ws[w][j * 4 + 2];
                vc += acc_ws[w][j * 4 + 3];
            }
        }
        rsum_p[tid * PBLK + bid] = vr;
        r2_p[tid * PBLK + bid]   = v2;
        ov_p[tid * PBLK + bid]   = vo;
        cnt_p[tid * PBLK + bid]  = vc;
    }
}

// ---------------- fallback path (gather + LDS atomics) ----------------

__global__ __launch_bounds__(FB_BLK) void pass1_fb(
    const int* __restrict__ idx0, const int* __restrict__ idx1,
    const float* __restrict__ attr, const float4* __restrict__ A,
    float* __restrict__ rsum_p, float* __restrict__ r2_p,
    float* __restrict__ ov_p, float* __restrict__ cnt_p) {
    __shared__ float sb_r[NCOPY*CSTR], sb_r2[NCOPY*CSTR], sb_ov[NCOPY*CSTR], sb_c[NCOPY*CSTR];
    int tid = threadIdx.x;
    for (int i = tid; i < NCOPY*CSTR; i += FB_BLK) { sb_r[i]=0.f; sb_r2[i]=0.f; sb_ov[i]=0.f; sb_c[i]=0.f; }
    __syncthreads();
    const int copy_off = (tid & (NCOPY - 1)) * CSTR;
    const int4* v0 = (const int4*)idx0;
    const int4* v1 = (const int4*)idx1;
    const float4* va = (const float4*)attr;
    const int gid = blockIdx.x * FB_BLK + tid;
    const int GRID = FB_NBLK * FB_BLK;
    for (int it = 0; it < 4; ++it) {
        int i = gid + it * GRID;
        int4 s4 = v0[i]; int4 t4 = v1[i]; float4 d4 = va[i];
        int   ss[4] = {s4.x, s4.y, s4.z, s4.w};
        int   tt[4] = {t4.x, t4.y, t4.z, t4.w};
        float dd[4] = {d4.x, d4.y, d4.z, d4.w};
        #pragma unroll
        for (int k = 0; k < 4; ++k) {
            float4 as_ = A[ss[k]], at_ = A[tt[k]];
            int g = (int)(__float_as_uint(as_.z) & 63u);
            int b = copy_off + g;
            float dx = as_.x - at_.x, dy = as_.y - at_.y;
            float eu = fsqrt_fast(dx * dx + dy * dy);
            float r = eu * frcp(dd[k]);
            atomicAdd(&sb_r[b], r);
            atomicAdd(&sb_r2[b], r * r);
            float ox = fmaxf((as_.z + at_.z) * 0.5f - fabsf(dx), 0.f);
            float oy = fmaxf((as_.w + at_.w) * 0.5f - fabsf(dy), 0.f);
            atomicAdd(&sb_ov[b], (ox * oy) * frcp(as_.z + as_.w + at_.z + at_.w));
            atomicAdd(&sb_c[b], 1.f);
        }
    }
    __syncthreads();
    if (tid < NG) {
        float r = 0.f, r2 = 0.f, ov = 0.f, c = 0.f;
        #pragma unroll
        for (int cp = 0; cp < NCOPY; ++cp) {
            int b = cp * CSTR + tid;
            r += sb_r[b]; r2 += sb_r2[b]; ov += sb_ov[b]; c += sb_c[b];
        }
        int o = tid * FB_NBLK + blockIdx.x;
        rsum_p[o] = r; r2_p[o] = r2; ov_p[o] = ov; cnt_p[o] = c;
    }
}

// ---------------- host ----------------

extern "C" void kernel_launch(void* const* d_in, const int* in_sizes, int n_in,
                              void* d_out, int out_size, void* d_ws, size_t ws_size,
                              hipStream_t stream) {
    const float* node_pos   = (const float*)d_in[0];
    const float* node_sizes = (const float*)d_in[1];
    const float* attr       = (const float*)d_in[2];
    const int*   eidx       = (const int*)d_in[3];
    const int*   batch      = (const int*)d_in[4];
    float* out = (float*)d_out;
    unsigned* ws = (unsigned*)d_ws;
    const int* idx0 = eidx;
    const int* idx1 = eidx + NE;

    // sorted-path layout (u32 units)
    const size_t o_srt    = 0;                               // 2*NE
    const size_t o_rel    = o_srt + (size_t)2 * NE;          // NBUCK*SBLK
    const size_t o_rowtot = o_rel + (size_t)NBUCK * SBLK;
    const size_t o_gbase  = o_rowtot + 1024;
    const size_t o_A      = o_gbase + 1028;                  // 16B-aligned
    const size_t o_part   = o_A + (size_t)4 * NN;
    const size_t o_small  = o_part + (size_t)4 * NG * PBLK;
    const size_t need     = (o_small + 256) * 4;

    if (ws_size >= need) {
        unsigned* rel    = ws + o_rel;
        unsigned* rowtot = ws + o_rowtot;
        unsigned* gbase  = ws + o_gbase;
        uvec2*    srt    = (uvec2*)(ws + o_srt);
        float4* A = (float4*)(ws + o_A);
        float* rsum_p = (float*)(ws + o_part);
        float* r2_p   = rsum_p + NG * PBLK;
        float* ov_p   = r2_p + NG * PBLK;
        float* cnt_p  = ov_p + NG * PBLK;
        float* comb   = (float*)(ws + o_small);

        build_A_kernel<<<NN / 256, 256, 0, stream>>>((const float2*)node_pos,
                                                     (const float2*)node_sizes, batch, A);
        khist<<<SBLK, 512, 0, stream>>>(idx0, idx1, rel);
        kscan16<<<NBUCK / 16, 512, 0, stream>>>(rel, rowtot);
        kscan_base<<<1, 1024, 0, stream>>>(rowtot, gbase);
        kscatter<<<SBLK, 1024, 0, stream>>>(idx0, idx1, attr, rel, gbase, srt);
        kproc1<<<PBLK, BLKP, 0, stream>>>(srt, gbase, A, rsum_p, r2_p, ov_p, cnt_p);
        reduce_final1<<<NG, 256, 0, stream>>>(rsum_p, r2_p, ov_p, cnt_p, batch, PBLK, comb);
        final_kernel<<<1, 64, 0, stream>>>(comb, out);
    } else {
        // fallback: gather path (~6.3 MB ws)
        const int P = NG * FB_NBLK;
        float* rsum_p = (float*)ws;
        float* r2_p   = rsum_p + P;
        float* ov_p   = r2_p + P;
        float* cnt_p  = ov_p + P;
        float* comb   = cnt_p + P;
        float4* A = (float4*)(comb + 64);

        build_A_kernel<<<NN / 256, 256, 0, stream>>>((const float2*)node_pos,
                                                     (const float2*)node_sizes, batch, A);
        pass1_fb<<<FB_NBLK, FB_BLK, 0, stream>>>(idx0, idx1, attr, A, rsum_p, r2_p, ov_p, cnt_p);
        reduce_final1<<<NG, 256, 0, stream>>>(rsum_p, r2_p, ov_p, cnt_p, batch, FB_NBLK, comb);
        final_kernel<<<1, 64, 0, stream>>>(comb, out);
    }
}